// Round 4
// baseline (41412.369 us; speedup 1.0000x reference)
//
#include <hip/hip_runtime.h>
#include <hip/hip_fp16.h>

// B=32, T=128, Din=H=C=1024, S=128.
// R4: persistent cooperative kernel (R3 structure) with the phase-A LDS
// overlap bug fixed (two-chunk staging, stride 3088B per 16-batch row, as
// validated in R2) and a hardened all-thread-fence grid barrier (G16:
// cross-XCD L2 non-coherence).
//
// MFMA 16x16x32_f16 layout (guide §3, m89-verified):
//   A: lane l, elem j -> A[l&15][(l>>4)*8+j]
//   B: lane l, elem j -> B[(l>>4)*8+j][l&15]
//   D: lane l, reg  r -> D[(l>>4)*4+r][l&15]

typedef _Float16 f16x8 __attribute__((ext_vector_type(8)));
typedef float f32x4 __attribute__((ext_vector_type(4)));

// ---- workspace layout (bytes) ----
#define OFF_XF16  ((size_t)0)           // [32][128][1024] f16     8,388,608
#define OFF_WP    ((size_t)8388608)     // [256][96][64][8] f16   25,165,824
#define OFF_WHP   ((size_t)33554432)    // [64][32][64][8] f16     2,097,152
#define OFF_BCAT  ((size_t)35651584)    // [1024][2048] f16        4,194,304
#define OFF_KPRE  ((size_t)39845888)    // [4096][1024] f16 row-major 8,388,608
#define OFF_CWT   ((size_t)48234496)    // [32][1024][128] f16     8,388,608
#define OFF_BIASR ((size_t)56623104)    // [4096] f32                 16,384
#define OFF_H2    ((size_t)56770560)    // [2][32][1024] f16         131,072
#define OFF_ATTN  ((size_t)56901632)    // [32][1024] f16             65,536
#define OFF_SC    ((size_t)56967168)    // [32][128] f32              16,384
#define OFF_BAR   ((size_t)56983552)    // [4] u32 barrier state

// ---------------- one-time kernels ----------------

__global__ __launch_bounds__(256) void k_cvt_x(const float* __restrict__ x, __half* __restrict__ xf) {
  int i = blockIdx.x * 256 + threadIdx.x;
  float4 v = ((const float4*)x)[i];
  __half h4[4] = {__float2half(v.x), __float2half(v.y), __float2half(v.z), __float2half(v.w)};
  ((float2*)xf)[i] = *(float2*)h4;
}

__global__ __launch_bounds__(256) void k_build_bcat(const float* __restrict__ wq,
                                                    const float* __restrict__ wout,
                                                    __half* __restrict__ bcat) {
  int j = blockIdx.x * 256 + threadIdx.x;
  int c = blockIdx.y;
  float v = (j < 1024) ? wq[c * 1024 + j] : wout[(size_t)(j - 1024) * 2048 + c];
  bcat[c * 2048 + j] = __float2half(v);
}

// pack gate weights into MFMA A-fragment stream: wp[mt][ks][l][8]
// packed row r' = mt*16 + (l&15); original row = gate*1024 + u, r' = u*4+gate
__global__ __launch_bounds__(256) void k_pack_wp(const float* __restrict__ wih,
                                                 const float* __restrict__ whh,
                                                 __half* __restrict__ wpo) {
  int mt = blockIdx.x;
  int tid = threadIdx.x;
  int ks = blockIdx.y * 4 + (tid >> 6);
  int l = tid & 63;
  int rp = mt * 16 + (l & 15);
  int u = rp >> 2, g = rp & 3;
  int row = g * 1024 + u;
  int k = ks * 32 + (l >> 4) * 8;
  const float* src = (k < 2048) ? (wih + (size_t)row * 2048 + k)
                                : (whh + (size_t)row * 1024 + (k - 2048));
  float4 a = *(const float4*)src;
  float4 b = *(const float4*)(src + 4);
  __half o[8] = {__float2half(a.x), __float2half(a.y), __float2half(a.z), __float2half(a.w),
                 __float2half(b.x), __float2half(b.y), __float2half(b.z), __float2half(b.w)};
  *(float4*)(wpo + (((size_t)mt * 96 + ks) * 64 + l) * 8) = *(float4*)o;
}

__global__ __launch_bounds__(256) void k_pack_whp(const float* __restrict__ wout,
                                                  __half* __restrict__ wpo) {
  int nt = blockIdx.x;
  int tid = threadIdx.x;
  int ks = blockIdx.y * 4 + (tid >> 6);
  int l = tid & 63;
  int row = nt * 16 + (l & 15);
  int k = ks * 32 + (l >> 4) * 8;
  const float* src = wout + (size_t)row * 2048 + 1024 + k;
  float4 a = *(const float4*)src;
  float4 b = *(const float4*)(src + 4);
  __half o[8] = {__float2half(a.x), __float2half(a.y), __float2half(a.z), __float2half(a.w),
                 __float2half(b.x), __float2half(b.y), __float2half(b.z), __float2half(b.w)};
  *(float4*)(wpo + (((size_t)nt * 32 + ks) * 64 + l) * 8) = *(float4*)o;
}

__global__ __launch_bounds__(256) void k_bias_r(const float* __restrict__ bih,
                                                const float* __restrict__ bhh,
                                                float* __restrict__ biasr) {
  int i = blockIdx.x * 256 + threadIdx.x;
  int u = i >> 2, g = i & 3;
  biasr[i] = bih[g * 1024 + u] + bhh[g * 1024 + u];
}

// precompute GEMM: [4096 x 1024] fp32 @ [1024 x 2048] f16.
// n<1024 -> kpre[m][n] row-major ; n>=1024 -> CWT[b][n-1024][s] transposed
__global__ __launch_bounds__(256) void k_pregemm(const float* __restrict__ Af,
                                                 const __half* __restrict__ Bh,
                                                 __half* __restrict__ kpre,
                                                 __half* __restrict__ cwt) {
  __shared__ __half As[32][68];
  __shared__ __half Bs[32][72];
  int tid = threadIdx.x;
  int tx = tid & 15, ty = tid >> 4;
  int m0 = blockIdx.x * 64;
  int n0 = blockIdx.y * 64;
  float acc[4][4] = {};
  int arow = tid >> 2;
  int akq = (tid & 3) * 8;
  int brow = tid >> 3;
  int bcol = (tid & 7) * 8;

  for (int k0 = 0; k0 < 1024; k0 += 32) {
    const float* ap = Af + (size_t)(m0 + arow) * 1024 + k0 + akq;
    float4 a0 = *(const float4*)ap;
    float4 a1 = *(const float4*)(ap + 4);
    As[akq + 0][arow] = __float2half(a0.x);
    As[akq + 1][arow] = __float2half(a0.y);
    As[akq + 2][arow] = __float2half(a0.z);
    As[akq + 3][arow] = __float2half(a0.w);
    As[akq + 4][arow] = __float2half(a1.x);
    As[akq + 5][arow] = __float2half(a1.y);
    As[akq + 6][arow] = __float2half(a1.z);
    As[akq + 7][arow] = __float2half(a1.w);
    float4 bv = *(const float4*)(Bh + (size_t)(k0 + brow) * 2048 + n0 + bcol);
    *(float4*)&Bs[brow][bcol] = bv;
    __syncthreads();
#pragma unroll
    for (int k = 0; k < 32; ++k) {
      float2 avv = *(const float2*)&As[k][ty * 4];
      float2 bvv = *(const float2*)&Bs[k][tx * 4];
      const __half* ah = (const __half*)&avv;
      const __half* bh2 = (const __half*)&bvv;
#pragma unroll
      for (int i = 0; i < 4; ++i) {
        float af = __half2float(ah[i]);
#pragma unroll
        for (int j = 0; j < 4; ++j)
          acc[i][j] = fmaf(af, __half2float(bh2[j]), acc[i][j]);
      }
    }
    __syncthreads();
  }

  if (n0 < 1024) {
#pragma unroll
    for (int i = 0; i < 4; ++i) {
      int m = m0 + ty * 4 + i;
      __half o4[4] = {__float2half(acc[i][0]), __float2half(acc[i][1]),
                      __float2half(acc[i][2]), __float2half(acc[i][3])};
      *(float2*)&kpre[(size_t)m * 1024 + n0 + tx * 4] = *(float2*)o4;
    }
  } else {
    int b = m0 >> 7;
    int s0 = (m0 & 127) + ty * 4;
#pragma unroll
    for (int j = 0; j < 4; ++j) {
      int nl = (n0 - 1024) + tx * 4 + j;
      __half o4[4] = {__float2half(acc[0][j]), __float2half(acc[1][j]),
                      __float2half(acc[2][j]), __float2half(acc[3][j])};
      *(float2*)&cwt[((size_t)b * 1024 + nl) * 128 + s0] = *(float2*)o4;
    }
  }
}

// ---------------- grid barrier (agent scope, all-thread fences, fail-fast) ----------------

__device__ __forceinline__ void gridbar(unsigned* bar) {
  __threadfence();   // each thread: release its own stores to agent scope
  __syncthreads();
  if (threadIdx.x == 0) {
    if (__hip_atomic_load(&bar[2], __ATOMIC_RELAXED, __HIP_MEMORY_SCOPE_AGENT) == 0u) {
      unsigned g = __hip_atomic_load(&bar[1], __ATOMIC_RELAXED, __HIP_MEMORY_SCOPE_AGENT);
      unsigned a = __hip_atomic_fetch_add(&bar[0], 1u, __ATOMIC_ACQ_REL, __HIP_MEMORY_SCOPE_AGENT);
      if (a == 255u) {
        __hip_atomic_store(&bar[0], 0u, __ATOMIC_RELAXED, __HIP_MEMORY_SCOPE_AGENT);
        __hip_atomic_store(&bar[1], g + 1u, __ATOMIC_RELEASE, __HIP_MEMORY_SCOPE_AGENT);
      } else {
        unsigned spins = 0;
        while (__hip_atomic_load(&bar[1], __ATOMIC_ACQUIRE, __HIP_MEMORY_SCOPE_AGENT) == g) {
          __builtin_amdgcn_s_sleep(2);
          if (++spins > 400000u) {  // fail fast instead of hang
            __hip_atomic_store(&bar[2], 1u, __ATOMIC_RELAXED, __HIP_MEMORY_SCOPE_AGENT);
            break;
          }
        }
      }
    }
  }
  __syncthreads();
  __threadfence();   // each thread: acquire (drop stale cached lines)
}

// ---------------- persistent kernel ----------------
// LDS map (phases barrier-separated):
//  A: inp 16x3088B @0 (49408) | redA @49408 (6144)         = 55552
//  B: hs2 @0 (2048)
//  C: hsl 16x2064B @0 (33024) | al @33024 (8448) | redC @41472 (7168) | cx @48640 (2048)

__global__ __launch_bounds__(512, 2) void k_persist(
    const __half* __restrict__ xf, const f16x8* __restrict__ wp,
    const f16x8* __restrict__ whp, const __half* __restrict__ kpre,
    const __half* __restrict__ cwt, const float* __restrict__ biasr,
    const float* __restrict__ bout, __half* __restrict__ hbuf,
    __half* __restrict__ attn, float* __restrict__ scores,
    float* __restrict__ out, unsigned* __restrict__ bar) {
  __shared__ __align__(16) char smem[55552];
  int tid = threadIdx.x;
  int blk = blockIdx.x;
  int w = tid >> 6, l = tid & 63;
  int rl = l & 15, kg = l >> 4;

  // ---- phase A roles: block = (rblk 0..127 row-block) x (bh2 batch half)
  int rblk = blk >> 1, bh2 = blk & 1;
  int mh = w & 1, kq = w >> 1;       // wave: row-subtile, k-quarter
  int mtA = rblk * 2 + mh;           // packed 16-row tile id

  // register-resident gate weights: 24 frags (96 VGPR)
  // wa[c*12+q] covers ks = c*48 + kq*12 + q  (chunk-local position kq*12+q)
  f16x8 wa[24];
#pragma unroll
  for (int c = 0; c < 2; ++c)
#pragma unroll
    for (int q = 0; q < 12; ++q)
      wa[c * 12 + q] = wp[((size_t)mtA * 96 + c * 48 + kq * 12 + q) * 64 + l];

  // phase C roles: blocks 0..127 active: (nt 0..63) x (bhc)
  bool actC = blk < 128;
  int nt = blk >> 1, bhc = blk & 1;
  f16x8 wc[4] = {};
  if (actC) {
#pragma unroll
    for (int q = 0; q < 4; ++q)
      wc[q] = whp[(((size_t)nt * 32) + w * 4 + q) * 64 + l];
  }

  float4 bvA = *(const float4*)&biasr[mtA * 16 + kg * 4];   // used by w<2
  float4 bo4 = {0, 0, 0, 0};
  if (actC) bo4 = *(const float4*)&bout[nt * 16 + kg * 4];  // used by w==0

  float creg = 0.f;   // cell state for (u = rblk*8+mh*4+kg, b = bh2*16+rl), w<2

  __half* inp = (__half*)smem;
  float* redA = (float*)(smem + 49408);
  __half* hs2 = (__half*)smem;
  __half* hsl = (__half*)smem;
  float* al   = (float*)(smem + 33024);
  float* redC = (float*)(smem + 41472);
  float* cx   = (float*)(smem + 48640);

  // phase B roles
  int bbB = blk >> 3, s0B = (blk & 7) * 16;

  // phase A staging roles
  int b0 = tid >> 5, c0 = tid & 31;   // 16 rows x 32 stagers

  for (int t = 0; t < 128; ++t) {
    int cur = t & 1;
    __half* hcur = hbuf + cur * 32768;
    __half* hprev = hbuf + (cur ^ 1) * 32768;

    // ======== phase A: gates MFMA + cell ========
    {
      int bb = bh2 * 16 + b0;
      const __half* xrow = xf + (((size_t)bb * 128 + t) << 10);
      const __half* arow = attn + ((size_t)bb << 10);
      const __half* hrow = hprev + ((size_t)bb << 10);
      char* drow = (char*)inp + b0 * 3088;
      const char* brow = (const char*)inp + rl * 3088 + kg * 16;
      f32x4 acc0 = {0, 0, 0, 0}, acc1 = {0, 0, 0, 0};

      for (int c = 0; c < 2; ++c) {
        // stage chunk c: 16 rows x 1536 halves (192 x 16B per row), 6/thread
#pragma unroll
        for (int j = 0; j < 6; ++j) {
          int u = c0 + 32 * j;              // 0..191
          int k0 = c * 1536 + u * 8;
          float4 v;
          if (t == 0 && k0 >= 1024) { v.x = v.y = v.z = v.w = 0.f; }
          else if (k0 < 1024)       v = *(const float4*)(xrow + k0);
          else if (k0 < 2048)       v = *(const float4*)(arow + (k0 - 1024));
          else                      v = *(const float4*)(hrow + (k0 - 2048));
          *(float4*)(drow + u * 16) = v;
        }
        __syncthreads();
#pragma unroll
        for (int q = 0; q < 12; q += 2) {
          f16x8 bf0 = *(const f16x8*)(brow + (kq * 12 + q) * 64);
          f16x8 bf1 = *(const f16x8*)(brow + (kq * 12 + q + 1) * 64);
          acc0 = __builtin_amdgcn_mfma_f32_16x16x32_f16(wa[c * 12 + q], bf0, acc0, 0, 0, 0);
          acc1 = __builtin_amdgcn_mfma_f32_16x16x32_f16(wa[c * 12 + q + 1], bf1, acc1, 0, 0, 0);
        }
        __syncthreads();
      }
      f32x4 acc;
      acc[0] = acc0[0] + acc1[0]; acc[1] = acc0[1] + acc1[1];
      acc[2] = acc0[2] + acc1[2]; acc[3] = acc0[3] + acc1[3];
      if (kq >= 1) *(f32x4*)&redA[(((kq - 1) * 2 + mh) * 64 + l) * 4] = acc;
      __syncthreads();
      if (w < 2) {   // kq==0, mh = w
#pragma unroll
        for (int p = 0; p < 3; ++p) {
          f32x4 o = *(f32x4*)&redA[((p * 2 + mh) * 64 + l) * 4];
          acc[0] += o[0]; acc[1] += o[1]; acc[2] += o[2]; acc[3] += o[3];
        }
        float gi = acc[0] + bvA.x;
        float gf = acc[1] + bvA.y;
        float gg = acc[2] + bvA.z;
        float go = acc[3] + bvA.w;
        float si = 1.f / (1.f + __expf(-gi));
        float sf = 1.f / (1.f + __expf(-gf));
        float so = 1.f / (1.f + __expf(-go));
        creg = sf * creg + si * tanhf(gg);
        int u = rblk * 8 + mh * 4 + kg;
        int b = bh2 * 16 + rl;
        hcur[((size_t)b << 10) + u] = __float2half(so * tanhf(creg));
      }
    }
    gridbar(bar);

    // ======== phase B: scores ========
    {
      if (tid < 128)
        *(float4*)&hs2[tid * 8] = *(const float4*)(hcur + ((size_t)bbB << 10) + tid * 8);
      __syncthreads();
      int sr = s0B + w * 2 + (l >> 5);
      int lk = l & 31;
      const __half* krow = kpre + ((size_t)(bbB * 128 + sr) << 10);
      float p = 0.f;
#pragma unroll
      for (int it = 0; it < 4; ++it) {
        int k = it * 256 + lk * 8;
        f16x8 kv = *(const f16x8*)(krow + k);
        f16x8 hv = *(const f16x8*)&hs2[k];
#pragma unroll
        for (int e = 0; e < 8; ++e) p = fmaf((float)kv[e], (float)hv[e], p);
      }
#pragma unroll
      for (int off = 16; off; off >>= 1) p += __shfl_xor(p, off);
      if (lk == 0) scores[bbB * 128 + sr] = p;
    }
    gridbar(bar);

    // ======== phase C: softmax + ctx + h-proj + tanh ========
    if (actC) {
      // stage h half (16 batches)
#pragma unroll
      for (int i2 = 0; i2 < 4; ++i2) {
        int f = i2 * 512 + tid;
        int b2 = f >> 7, u2 = f & 127;
        float4 v = *(const float4*)(hcur + (((size_t)bhc * 16 + b2) << 10) + u2 * 8);
        *(float4*)((char*)hsl + b2 * 2064 + u2 * 16) = v;
      }
      // softmax: 32 lanes per batch
      {
        int bl = tid >> 5, lj = tid & 31;
        const float* srow = scores + (bhc * 16 + bl) * 128;
        float4 sv = *(const float4*)(srow + lj * 4);
        float m = fmaxf(fmaxf(sv.x, sv.y), fmaxf(sv.z, sv.w));
#pragma unroll
        for (int off = 16; off; off >>= 1) m = fmaxf(m, __shfl_xor(m, off));
        float e0 = __expf(sv.x - m), e1 = __expf(sv.y - m);
        float e2 = __expf(sv.z - m), e3 = __expf(sv.w - m);
        float s = e0 + e1 + e2 + e3;
#pragma unroll
        for (int off = 16; off; off >>= 1) s += __shfl_xor(s, off);
        float inv = 1.f / s;
        float4 av = {e0 * inv, e1 * inv, e2 * inv, e3 * inv};
        *(float4*)&al[bl * 132 + lj * 4] = av;
      }
      __syncthreads();
      // h-proj MFMA (K split across 8 waves)
      f32x4 acc2 = {0, 0, 0, 0};
      const char* brow2 = (const char*)hsl + rl * 2064 + kg * 16;
#pragma unroll
      for (int q = 0; q < 4; ++q) {
        f16x8 bf = *(const f16x8*)(brow2 + (w * 4 + q) * 64);
        acc2 = __builtin_amdgcn_mfma_f32_16x16x32_f16(wc[q], bf, acc2, 0, 0, 0);
      }
      // ctx partials: thread -> (n_l, b_l, s-half)
      {
        int nl2 = tid & 15, bl2 = (tid >> 4) & 15, sh = tid >> 8;
        const __half* crow = cwt + (((size_t)(bhc * 16 + bl2) << 10) + nt * 16 + nl2) * 128 + sh * 64;
        const float* arow2 = &al[bl2 * 132 + sh * 64];
        float pc = 0.f;
#pragma unroll
        for (int s2 = 0; s2 < 64; s2 += 8) {
          f16x8 cv = *(const f16x8*)(crow + s2);
#pragma unroll
          for (int e = 0; e < 8; ++e) pc = fmaf(arow2[s2 + e], (float)cv[e], pc);
        }
        cx[sh * 256 + bl2 * 16 + nl2] = pc;
      }
      if (w >= 1) *(f32x4*)&redC[((w - 1) * 64 + l) * 4] = acc2;
      __syncthreads();
      if (w == 0) {
#pragma unroll
        for (int p3 = 0; p3 < 7; ++p3) {
          f32x4 o = *(f32x4*)&redC[(p3 * 64 + l) * 4];
          acc2[0] += o[0]; acc2[1] += o[1]; acc2[2] += o[2]; acc2[3] += o[3];
        }
        int bfin = bhc * 16 + rl;
        int n0 = nt * 16 + kg * 4;
        float vo[4];
#pragma unroll
        for (int r = 0; r < 4; ++r) {
          float cv2 = cx[rl * 16 + kg * 4 + r] + cx[256 + rl * 16 + kg * 4 + r];
          float bb2 = (r == 0) ? bo4.x : (r == 1) ? bo4.y : (r == 2) ? bo4.z : bo4.w;
          vo[r] = tanhf(acc2[r] + cv2 + bb2);
        }
        __half o4[4] = {__float2half(vo[0]), __float2half(vo[1]),
                        __float2half(vo[2]), __float2half(vo[3])};
        *(float2*)&attn[((size_t)bfin << 10) + n0] = *(float2*)o4;
        float4 ov = {vo[0], vo[1], vo[2], vo[3]};
        *(float4*)&out[(((size_t)bfin * 128 + t) << 10) + n0] = ov;
      }
    }
    gridbar(bar);
  }
}

// ---------------- launcher ----------------

extern "C" void kernel_launch(void* const* d_in, const int* in_sizes, int n_in,
                              void* d_out, int out_size, void* d_ws, size_t ws_size,
                              hipStream_t stream) {
  const float* x    = (const float*)d_in[0];
  const float* ctxp = (const float*)d_in[1];
  const float* wih  = (const float*)d_in[2];
  const float* whh  = (const float*)d_in[3];
  const float* bih  = (const float*)d_in[4];
  const float* bhh  = (const float*)d_in[5];
  const float* wq   = (const float*)d_in[6];
  const float* wout = (const float*)d_in[7];
  const float* bo   = (const float*)d_in[8];
  float* out = (float*)d_out;
  char* ws = (char*)d_ws;

  __half* xf    = (__half*)(ws + OFF_XF16);
  __half* wpq   = (__half*)(ws + OFF_WP);
  __half* whpq  = (__half*)(ws + OFF_WHP);
  __half* bcat  = (__half*)(ws + OFF_BCAT);
  __half* kpre  = (__half*)(ws + OFF_KPRE);
  __half* cwt   = (__half*)(ws + OFF_CWT);
  float*  biasr = (float*)(ws + OFF_BIASR);
  __half* hbuf  = (__half*)(ws + OFF_H2);
  __half* attn  = (__half*)(ws + OFF_ATTN);
  float*  sc    = (float*)(ws + OFF_SC);
  unsigned* bar = (unsigned*)(ws + OFF_BAR);

  hipMemsetAsync(ws + OFF_BAR, 0, 16, stream);

  hipLaunchKernelGGL(k_cvt_x, dim3(4096), dim3(256), 0, stream, x, xf);
  hipLaunchKernelGGL(k_build_bcat, dim3(8, 1024), dim3(256), 0, stream, wq, wout, bcat);
  hipLaunchKernelGGL(k_pack_wp, dim3(256, 24), dim3(256), 0, stream, wih, whh, wpq);
  hipLaunchKernelGGL(k_pack_whp, dim3(64, 8), dim3(256), 0, stream, wout, whpq);
  hipLaunchKernelGGL(k_bias_r, dim3(16), dim3(256), 0, stream, bih, bhh, biasr);
  hipLaunchKernelGGL(k_pregemm, dim3(64, 32), dim3(256), 0, stream, ctxp, bcat, kpre, cwt);

  const f16x8* wpv = (const f16x8*)wpq;
  const f16x8* whpv = (const f16x8*)whpq;
  const __half* xfc = xf;
  const __half* kprec = kpre;
  const __half* cwtc = cwt;
  const float* biasrc = biasr;
  const float* boc = bo;
  void* args[] = {(void*)&xfc, (void*)&wpv, (void*)&whpv, (void*)&kprec, (void*)&cwtc,
                  (void*)&biasrc, (void*)&boc, (void*)&hbuf, (void*)&attn, (void*)&sc,
                  (void*)&out, (void*)&bar};
  hipLaunchCooperativeKernel((void*)k_persist, dim3(256), dim3(512), args, 0, stream);
}

// Round 5
// 5228.533 us; speedup vs baseline: 7.9205x; 7.9205x over previous
//
#include <hip/hip_runtime.h>
#include <hip/hip_fp16.h>

// B=32, T=128, Din=H=C=1024, S=128.
// R5: persistent cooperative kernel; cross-block data via RELAXED AGENT-scope
// atomics (sc0/sc1 -> coherent through Infinity Cache, no L2 flushes); grid
// barrier with NO cache-flushing fences (R4's per-wave __threadfence was an
// L2-writeback storm: 105us/barrier -> 40.5ms).
//
// MFMA 16x16x32_f16 layout (guide §3, m89-verified):
//   A: lane l, elem j -> A[l&15][(l>>4)*8+j]
//   B: lane l, elem j -> B[(l>>4)*8+j][l&15]
//   D: lane l, reg  r -> D[(l>>4)*4+r][l&15]

typedef _Float16 f16x8 __attribute__((ext_vector_type(8)));
typedef float f32x4 __attribute__((ext_vector_type(4)));
typedef unsigned long long u64;

// ---- workspace layout (bytes) ----
#define OFF_XF16  ((size_t)0)           // [32][128][1024] f16     8,388,608
#define OFF_WP    ((size_t)8388608)     // [256][96][64][8] f16   25,165,824
#define OFF_WHP   ((size_t)33554432)    // [64][32][64][8] f16     2,097,152
#define OFF_BCAT  ((size_t)35651584)    // [1024][2048] f16        4,194,304
#define OFF_KPRE  ((size_t)39845888)    // [4096][1024] f16 row-major 8,388,608
#define OFF_CWT   ((size_t)48234496)    // [32][1024][128] f16     8,388,608
#define OFF_BIASR ((size_t)56623104)    // [4096] f32                 16,384
#define OFF_H2    ((size_t)56770560)    // [2][32][1024] f16         131,072
#define OFF_ATTN  ((size_t)56901632)    // [32][1024] f16             65,536
#define OFF_SC    ((size_t)56967168)    // [32][128] f32              16,384
#define OFF_BAR   ((size_t)56983552)    // [4] u32 barrier state

// ---- agent-scope coherent access helpers (bypass non-coherent L2) ----
__device__ __forceinline__ u64 aload64(const void* p) {
  return __hip_atomic_load((const u64*)p, __ATOMIC_RELAXED, __HIP_MEMORY_SCOPE_AGENT);
}
__device__ __forceinline__ void astore64(void* p, u64 v) {
  __hip_atomic_store((u64*)p, v, __ATOMIC_RELAXED, __HIP_MEMORY_SCOPE_AGENT);
}
__device__ __forceinline__ unsigned aload32(const void* p) {
  return __hip_atomic_load((const unsigned*)p, __ATOMIC_RELAXED, __HIP_MEMORY_SCOPE_AGENT);
}
__device__ __forceinline__ void astore32(void* p, unsigned v) {
  __hip_atomic_store((unsigned*)p, v, __ATOMIC_RELAXED, __HIP_MEMORY_SCOPE_AGENT);
}
__device__ __forceinline__ void astore16(void* p, unsigned short v) {
  __hip_atomic_store((unsigned short*)p, v, __ATOMIC_RELAXED, __HIP_MEMORY_SCOPE_AGENT);
}
__device__ __forceinline__ float4 aload128(const void* p) {
  float4 v;
  ((u64*)&v)[0] = aload64(p);
  ((u64*)&v)[1] = aload64((const char*)p + 8);
  return v;
}

// ---------------- one-time kernels ----------------

__global__ __launch_bounds__(256) void k_cvt_x(const float* __restrict__ x, __half* __restrict__ xf) {
  int i = blockIdx.x * 256 + threadIdx.x;
  float4 v = ((const float4*)x)[i];
  __half h4[4] = {__float2half(v.x), __float2half(v.y), __float2half(v.z), __float2half(v.w)};
  ((float2*)xf)[i] = *(float2*)h4;
}

__global__ __launch_bounds__(256) void k_build_bcat(const float* __restrict__ wq,
                                                    const float* __restrict__ wout,
                                                    __half* __restrict__ bcat) {
  int j = blockIdx.x * 256 + threadIdx.x;
  int c = blockIdx.y;
  float v = (j < 1024) ? wq[c * 1024 + j] : wout[(size_t)(j - 1024) * 2048 + c];
  bcat[c * 2048 + j] = __float2half(v);
}

// pack gate weights into MFMA A-fragment stream: wp[mt][ks][l][8]
// packed row r' = mt*16 + (l&15); original row = gate*1024 + u, r' = u*4+gate
__global__ __launch_bounds__(256) void k_pack_wp(const float* __restrict__ wih,
                                                 const float* __restrict__ whh,
                                                 __half* __restrict__ wpo) {
  int mt = blockIdx.x;
  int tid = threadIdx.x;
  int ks = blockIdx.y * 4 + (tid >> 6);
  int l = tid & 63;
  int rp = mt * 16 + (l & 15);
  int u = rp >> 2, g = rp & 3;
  int row = g * 1024 + u;
  int k = ks * 32 + (l >> 4) * 8;
  const float* src = (k < 2048) ? (wih + (size_t)row * 2048 + k)
                                : (whh + (size_t)row * 1024 + (k - 2048));
  float4 a = *(const float4*)src;
  float4 b = *(const float4*)(src + 4);
  __half o[8] = {__float2half(a.x), __float2half(a.y), __float2half(a.z), __float2half(a.w),
                 __float2half(b.x), __float2half(b.y), __float2half(b.z), __float2half(b.w)};
  *(float4*)(wpo + (((size_t)mt * 96 + ks) * 64 + l) * 8) = *(float4*)o;
}

__global__ __launch_bounds__(256) void k_pack_whp(const float* __restrict__ wout,
                                                  __half* __restrict__ wpo) {
  int nt = blockIdx.x;
  int tid = threadIdx.x;
  int ks = blockIdx.y * 4 + (tid >> 6);
  int l = tid & 63;
  int row = nt * 16 + (l & 15);
  int k = ks * 32 + (l >> 4) * 8;
  const float* src = wout + (size_t)row * 2048 + 1024 + k;
  float4 a = *(const float4*)src;
  float4 b = *(const float4*)(src + 4);
  __half o[8] = {__float2half(a.x), __float2half(a.y), __float2half(a.z), __float2half(a.w),
                 __float2half(b.x), __float2half(b.y), __float2half(b.z), __float2half(b.w)};
  *(float4*)(wpo + (((size_t)nt * 32 + ks) * 64 + l) * 8) = *(float4*)o;
}

__global__ __launch_bounds__(256) void k_bias_r(const float* __restrict__ bih,
                                                const float* __restrict__ bhh,
                                                float* __restrict__ biasr) {
  int i = blockIdx.x * 256 + threadIdx.x;
  int u = i >> 2, g = i & 3;
  biasr[i] = bih[g * 1024 + u] + bhh[g * 1024 + u];
}

// precompute GEMM: [4096 x 1024] fp32 @ [1024 x 2048] f16.
// n<1024 -> kpre[m][n] row-major ; n>=1024 -> CWT[b][n-1024][s] transposed
__global__ __launch_bounds__(256) void k_pregemm(const float* __restrict__ Af,
                                                 const __half* __restrict__ Bh,
                                                 __half* __restrict__ kpre,
                                                 __half* __restrict__ cwt) {
  __shared__ __half As[32][68];
  __shared__ __half Bs[32][72];
  int tid = threadIdx.x;
  int tx = tid & 15, ty = tid >> 4;
  int m0 = blockIdx.x * 64;
  int n0 = blockIdx.y * 64;
  float acc[4][4] = {};
  int arow = tid >> 2;
  int akq = (tid & 3) * 8;
  int brow = tid >> 3;
  int bcol = (tid & 7) * 8;

  for (int k0 = 0; k0 < 1024; k0 += 32) {
    const float* ap = Af + (size_t)(m0 + arow) * 1024 + k0 + akq;
    float4 a0 = *(const float4*)ap;
    float4 a1 = *(const float4*)(ap + 4);
    As[akq + 0][arow] = __float2half(a0.x);
    As[akq + 1][arow] = __float2half(a0.y);
    As[akq + 2][arow] = __float2half(a0.z);
    As[akq + 3][arow] = __float2half(a0.w);
    As[akq + 4][arow] = __float2half(a1.x);
    As[akq + 5][arow] = __float2half(a1.y);
    As[akq + 6][arow] = __float2half(a1.z);
    As[akq + 7][arow] = __float2half(a1.w);
    float4 bv = *(const float4*)(Bh + (size_t)(k0 + brow) * 2048 + n0 + bcol);
    *(float4*)&Bs[brow][bcol] = bv;
    __syncthreads();
#pragma unroll
    for (int k = 0; k < 32; ++k) {
      float2 avv = *(const float2*)&As[k][ty * 4];
      float2 bvv = *(const float2*)&Bs[k][tx * 4];
      const __half* ah = (const __half*)&avv;
      const __half* bh2 = (const __half*)&bvv;
#pragma unroll
      for (int i = 0; i < 4; ++i) {
        float af = __half2float(ah[i]);
#pragma unroll
        for (int j = 0; j < 4; ++j)
          acc[i][j] = fmaf(af, __half2float(bh2[j]), acc[i][j]);
      }
    }
    __syncthreads();
  }

  if (n0 < 1024) {
#pragma unroll
    for (int i = 0; i < 4; ++i) {
      int m = m0 + ty * 4 + i;
      __half o4[4] = {__float2half(acc[i][0]), __float2half(acc[i][1]),
                      __float2half(acc[i][2]), __float2half(acc[i][3])};
      *(float2*)&kpre[(size_t)m * 1024 + n0 + tx * 4] = *(float2*)o4;
    }
  } else {
    int b = m0 >> 7;
    int s0 = (m0 & 127) + ty * 4;
#pragma unroll
    for (int j = 0; j < 4; ++j) {
      int nl = (n0 - 1024) + tx * 4 + j;
      __half o4[4] = {__float2half(acc[0][j]), __float2half(acc[1][j]),
                      __float2half(acc[2][j]), __float2half(acc[3][j])};
      *(float2*)&cwt[((size_t)b * 1024 + nl) * 128 + s0] = *(float2*)o4;
    }
  }
}

// ---------------- grid barrier: no cache flushes ----------------
// Data coherence comes from sc1 atomics on the data itself. __syncthreads
// drains each wave's vmcnt (compiler emits waitcnt before s_barrier), so all
// of this block's coherent stores are globally visible before the arrive.

__device__ __forceinline__ void gridbar(unsigned* bar) {
  __syncthreads();
  if (threadIdx.x == 0) {
    asm volatile("s_waitcnt vmcnt(0) lgkmcnt(0)" ::: "memory");
    if (__hip_atomic_load(&bar[2], __ATOMIC_RELAXED, __HIP_MEMORY_SCOPE_AGENT) == 0u) {
      unsigned g = __hip_atomic_load(&bar[1], __ATOMIC_RELAXED, __HIP_MEMORY_SCOPE_AGENT);
      unsigned a = __hip_atomic_fetch_add(&bar[0], 1u, __ATOMIC_RELAXED, __HIP_MEMORY_SCOPE_AGENT);
      if (a == 255u) {
        __hip_atomic_store(&bar[0], 0u, __ATOMIC_RELAXED, __HIP_MEMORY_SCOPE_AGENT);
        asm volatile("s_waitcnt vmcnt(0)" ::: "memory");   // reset visible before bump
        __hip_atomic_store(&bar[1], g + 1u, __ATOMIC_RELAXED, __HIP_MEMORY_SCOPE_AGENT);
      } else {
        unsigned spins = 0;
        while (__hip_atomic_load(&bar[1], __ATOMIC_RELAXED, __HIP_MEMORY_SCOPE_AGENT) == g) {
          __builtin_amdgcn_s_sleep(1);
          if (++spins > 300000u) {  // fail fast instead of hang
            __hip_atomic_store(&bar[2], 1u, __ATOMIC_RELAXED, __HIP_MEMORY_SCOPE_AGENT);
            break;
          }
        }
      }
    }
    asm volatile("" ::: "memory");
  }
  __syncthreads();
}

// ---------------- persistent kernel ----------------
// LDS map (phases barrier-separated):
//  A: inp 16x3088B @0 (49408) | redA @49408 (6144)         = 55552
//  B: hs2 @0 (2048)
//  C: hsl 16x2064B @0 (33024) | al @33024 (8448) | redC @41472 (7168) | cx @48640 (2048)

__global__ __launch_bounds__(512, 2) void k_persist(
    const __half* __restrict__ xf, const f16x8* __restrict__ wp,
    const f16x8* __restrict__ whp, const __half* __restrict__ kpre,
    const __half* __restrict__ cwt, const float* __restrict__ biasr,
    const float* __restrict__ bout, __half* __restrict__ hbuf,
    __half* __restrict__ attn, float* __restrict__ scores,
    float* __restrict__ out, unsigned* __restrict__ bar) {
  __shared__ __align__(16) char smem[55552];
  int tid = threadIdx.x;
  int blk = blockIdx.x;
  int w = tid >> 6, l = tid & 63;
  int rl = l & 15, kg = l >> 4;

  // ---- phase A roles: block = (rblk 0..127 row-block) x (bh2 batch half)
  int rblk = blk >> 1, bh2 = blk & 1;
  int mh = w & 1, kq = w >> 1;       // wave: row-subtile, k-quarter
  int mtA = rblk * 2 + mh;           // packed 16-row tile id

  // register-resident gate weights: 24 frags (96 VGPR)
  f16x8 wa[24];
#pragma unroll
  for (int c = 0; c < 2; ++c)
#pragma unroll
    for (int q = 0; q < 12; ++q)
      wa[c * 12 + q] = wp[((size_t)mtA * 96 + c * 48 + kq * 12 + q) * 64 + l];

  // phase C roles: blocks 0..127 active: (nt 0..63) x (bhc)
  bool actC = blk < 128;
  int nt = blk >> 1, bhc = blk & 1;
  f16x8 wc[4] = {};
  if (actC) {
#pragma unroll
    for (int q = 0; q < 4; ++q)
      wc[q] = whp[(((size_t)nt * 32) + w * 4 + q) * 64 + l];
  }

  float4 bvA = *(const float4*)&biasr[mtA * 16 + kg * 4];   // used by w<2
  float4 bo4 = {0, 0, 0, 0};
  if (actC) bo4 = *(const float4*)&bout[nt * 16 + kg * 4];  // used by w==0

  float creg = 0.f;   // cell state for (u = rblk*8+mh*4+kg, b = bh2*16+rl), w<2

  __half* inp = (__half*)smem;
  float* redA = (float*)(smem + 49408);
  __half* hs2 = (__half*)smem;
  __half* hsl = (__half*)smem;
  float* al   = (float*)(smem + 33024);
  float* redC = (float*)(smem + 41472);
  float* cx   = (float*)(smem + 48640);

  // phase B roles
  int bbB = blk >> 3, s0B = (blk & 7) * 16;

  // phase A staging roles
  int b0 = tid >> 5, c0 = tid & 31;   // 16 rows x 32 stagers

  for (int t = 0; t < 128; ++t) {
    int cur = t & 1;
    __half* hcur = hbuf + cur * 32768;
    __half* hprev = hbuf + (cur ^ 1) * 32768;

    // ======== phase A: gates MFMA + cell ========
    {
      int bb = bh2 * 16 + b0;
      const __half* xrow = xf + (((size_t)bb * 128 + t) << 10);
      const __half* arow = attn + ((size_t)bb << 10);
      const __half* hrow = hprev + ((size_t)bb << 10);
      char* drow = (char*)inp + b0 * 3088;
      const char* brow = (const char*)inp + rl * 3088 + kg * 16;
      f32x4 acc0 = {0, 0, 0, 0}, acc1 = {0, 0, 0, 0};

      for (int c = 0; c < 2; ++c) {
        // stage chunk c: 16 rows x 1536 halves (192 x 16B per row), 6/thread
#pragma unroll
        for (int j = 0; j < 6; ++j) {
          int u = c0 + 32 * j;              // 0..191
          int k0 = c * 1536 + u * 8;
          float4 v;
          if (t == 0 && k0 >= 1024) { v.x = v.y = v.z = v.w = 0.f; }
          else if (k0 < 1024)       v = *(const float4*)(xrow + k0);
          else if (k0 < 2048)       v = aload128(arow + (k0 - 1024));   // coherent
          else                      v = aload128(hrow + (k0 - 2048));   // coherent
          *(float4*)(drow + u * 16) = v;
        }
        __syncthreads();
#pragma unroll
        for (int q = 0; q < 12; q += 2) {
          f16x8 bf0 = *(const f16x8*)(brow + (kq * 12 + q) * 64);
          f16x8 bf1 = *(const f16x8*)(brow + (kq * 12 + q + 1) * 64);
          acc0 = __builtin_amdgcn_mfma_f32_16x16x32_f16(wa[c * 12 + q], bf0, acc0, 0, 0, 0);
          acc1 = __builtin_amdgcn_mfma_f32_16x16x32_f16(wa[c * 12 + q + 1], bf1, acc1, 0, 0, 0);
        }
        __syncthreads();
      }
      f32x4 acc;
      acc[0] = acc0[0] + acc1[0]; acc[1] = acc0[1] + acc1[1];
      acc[2] = acc0[2] + acc1[2]; acc[3] = acc0[3] + acc1[3];
      if (kq >= 1) *(f32x4*)&redA[(((kq - 1) * 2 + mh) * 64 + l) * 4] = acc;
      __syncthreads();
      if (w < 2) {   // kq==0, mh = w
#pragma unroll
        for (int p = 0; p < 3; ++p) {
          f32x4 o = *(f32x4*)&redA[((p * 2 + mh) * 64 + l) * 4];
          acc[0] += o[0]; acc[1] += o[1]; acc[2] += o[2]; acc[3] += o[3];
        }
        float gi = acc[0] + bvA.x;
        float gf = acc[1] + bvA.y;
        float gg = acc[2] + bvA.z;
        float go = acc[3] + bvA.w;
        float si = 1.f / (1.f + __expf(-gi));
        float sf = 1.f / (1.f + __expf(-gf));
        float so = 1.f / (1.f + __expf(-go));
        creg = sf * creg + si * tanhf(gg);
        int u = rblk * 8 + mh * 4 + kg;
        int b = bh2 * 16 + rl;
        __half hv = __float2half(so * tanhf(creg));
        astore16(&hcur[((size_t)b << 10) + u], *(unsigned short*)&hv);   // coherent
      }
    }
    gridbar(bar);

    // ======== phase B: scores ========
    {
      if (tid < 128) {
        const __half* s = hcur + ((size_t)bbB << 10) + tid * 8;
        ((u64*)&hs2[tid * 8])[0] = aload64(s);          // coherent
        ((u64*)&hs2[tid * 8])[1] = aload64(s + 4);
      }
      __syncthreads();
      int sr = s0B + w * 2 + (l >> 5);
      int lk = l & 31;
      const __half* krow = kpre + ((size_t)(bbB * 128 + sr) << 10);
      float p = 0.f;
#pragma unroll
      for (int it = 0; it < 4; ++it) {
        int k = it * 256 + lk * 8;
        f16x8 kv = *(const f16x8*)(krow + k);
        f16x8 hv = *(const f16x8*)&hs2[k];
#pragma unroll
        for (int e = 0; e < 8; ++e) p = fmaf((float)kv[e], (float)hv[e], p);
      }
#pragma unroll
      for (int off = 16; off; off >>= 1) p += __shfl_xor(p, off);
      if (lk == 0) astore32(&scores[bbB * 128 + sr], __float_as_uint(p));   // coherent
    }
    gridbar(bar);

    // ======== phase C: softmax + ctx + h-proj + tanh ========
    if (actC) {
      // stage h half (16 batches) — coherent reads
#pragma unroll
      for (int i2 = 0; i2 < 4; ++i2) {
        int f = i2 * 512 + tid;
        int b2 = f >> 7, u2 = f & 127;
        const __half* s = hcur + (((size_t)bhc * 16 + b2) << 10) + u2 * 8;
        char* d = (char*)hsl + b2 * 2064 + u2 * 16;
        ((u64*)d)[0] = aload64(s);
        ((u64*)d)[1] = aload64(s + 4);
      }
      // softmax: 32 lanes per batch — coherent score reads
      {
        int bl = tid >> 5, lj = tid & 31;
        const float* srow = scores + (bhc * 16 + bl) * 128;
        float4 sv = aload128(srow + lj * 4);
        float m = fmaxf(fmaxf(sv.x, sv.y), fmaxf(sv.z, sv.w));
#pragma unroll
        for (int off = 16; off; off >>= 1) m = fmaxf(m, __shfl_xor(m, off));
        float e0 = __expf(sv.x - m), e1 = __expf(sv.y - m);
        float e2 = __expf(sv.z - m), e3 = __expf(sv.w - m);
        float s = e0 + e1 + e2 + e3;
#pragma unroll
        for (int off = 16; off; off >>= 1) s += __shfl_xor(s, off);
        float inv = 1.f / s;
        float4 av = {e0 * inv, e1 * inv, e2 * inv, e3 * inv};
        *(float4*)&al[bl * 132 + lj * 4] = av;
      }
      __syncthreads();
      // h-proj MFMA (K split across 8 waves)
      f32x4 acc2 = {0, 0, 0, 0};
      const char* brow2 = (const char*)hsl + rl * 2064 + kg * 16;
#pragma unroll
      for (int q = 0; q < 4; ++q) {
        f16x8 bf = *(const f16x8*)(brow2 + (w * 4 + q) * 64);
        acc2 = __builtin_amdgcn_mfma_f32_16x16x32_f16(wc[q], bf, acc2, 0, 0, 0);
      }
      // ctx partials: thread -> (n_l, b_l, s-half)
      {
        int nl2 = tid & 15, bl2 = (tid >> 4) & 15, sh = tid >> 8;
        const __half* crow = cwt + (((size_t)(bhc * 16 + bl2) << 10) + nt * 16 + nl2) * 128 + sh * 64;
        const float* arow2 = &al[bl2 * 132 + sh * 64];
        float pc = 0.f;
#pragma unroll
        for (int s2 = 0; s2 < 64; s2 += 8) {
          f16x8 cv = *(const f16x8*)(crow + s2);
#pragma unroll
          for (int e = 0; e < 8; ++e) pc = fmaf(arow2[s2 + e], (float)cv[e], pc);
        }
        cx[sh * 256 + bl2 * 16 + nl2] = pc;
      }
      if (w >= 1) *(f32x4*)&redC[((w - 1) * 64 + l) * 4] = acc2;
      __syncthreads();
      if (w == 0) {
#pragma unroll
        for (int p3 = 0; p3 < 7; ++p3) {
          f32x4 o = *(f32x4*)&redC[(p3 * 64 + l) * 4];
          acc2[0] += o[0]; acc2[1] += o[1]; acc2[2] += o[2]; acc2[3] += o[3];
        }
        int bfin = bhc * 16 + rl;
        int n0 = nt * 16 + kg * 4;
        float vo[4];
#pragma unroll
        for (int r = 0; r < 4; ++r) {
          float cv2 = cx[rl * 16 + kg * 4 + r] + cx[256 + rl * 16 + kg * 4 + r];
          float bb2 = (r == 0) ? bo4.x : (r == 1) ? bo4.y : (r == 2) ? bo4.z : bo4.w;
          vo[r] = tanhf(acc2[r] + cv2 + bb2);
        }
        __half o4[4] = {__float2half(vo[0]), __float2half(vo[1]),
                        __float2half(vo[2]), __float2half(vo[3])};
        astore64(&attn[((size_t)bfin << 10) + n0], *(u64*)o4);   // coherent
        float4 ov = {vo[0], vo[1], vo[2], vo[3]};
        *(float4*)&out[(((size_t)bfin * 128 + t) << 10) + n0] = ov;  // normal (read after kernel end)
      }
    }
    gridbar(bar);
  }
}

// ---------------- launcher ----------------

extern "C" void kernel_launch(void* const* d_in, const int* in_sizes, int n_in,
                              void* d_out, int out_size, void* d_ws, size_t ws_size,
                              hipStream_t stream) {
  const float* x    = (const float*)d_in[0];
  const float* ctxp = (const float*)d_in[1];
  const float* wih  = (const float*)d_in[2];
  const float* whh  = (const float*)d_in[3];
  const float* bih  = (const float*)d_in[4];
  const float* bhh  = (const float*)d_in[5];
  const float* wq   = (const float*)d_in[6];
  const float* wout = (const float*)d_in[7];
  const float* bo   = (const float*)d_in[8];
  float* out = (float*)d_out;
  char* ws = (char*)d_ws;

  __half* xf    = (__half*)(ws + OFF_XF16);
  __half* wpq   = (__half*)(ws + OFF_WP);
  __half* whpq  = (__half*)(ws + OFF_WHP);
  __half* bcat  = (__half*)(ws + OFF_BCAT);
  __half* kpre  = (__half*)(ws + OFF_KPRE);
  __half* cwt   = (__half*)(ws + OFF_CWT);
  float*  biasr = (float*)(ws + OFF_BIASR);
  __half* hbuf  = (__half*)(ws + OFF_H2);
  __half* attn  = (__half*)(ws + OFF_ATTN);
  float*  sc    = (float*)(ws + OFF_SC);
  unsigned* bar = (unsigned*)(ws + OFF_BAR);

  hipMemsetAsync(ws + OFF_BAR, 0, 16, stream);

  hipLaunchKernelGGL(k_cvt_x, dim3(4096), dim3(256), 0, stream, x, xf);
  hipLaunchKernelGGL(k_build_bcat, dim3(8, 1024), dim3(256), 0, stream, wq, wout, bcat);
  hipLaunchKernelGGL(k_pack_wp, dim3(256, 24), dim3(256), 0, stream, wih, whh, wpq);
  hipLaunchKernelGGL(k_pack_whp, dim3(64, 8), dim3(256), 0, stream, wout, whpq);
  hipLaunchKernelGGL(k_bias_r, dim3(16), dim3(256), 0, stream, bih, bhh, biasr);
  hipLaunchKernelGGL(k_pregemm, dim3(64, 32), dim3(256), 0, stream, ctxp, bcat, kpre, cwt);

  const f16x8* wpv = (const f16x8*)wpq;
  const f16x8* whpv = (const f16x8*)whpq;
  const __half* xfc = xf;
  const __half* kprec = kpre;
  const __half* cwtc = cwt;
  const float* biasrc = biasr;
  const float* boc = bo;
  void* args[] = {(void*)&xfc, (void*)&wpv, (void*)&whpv, (void*)&kprec, (void*)&cwtc,
                  (void*)&biasrc, (void*)&boc, (void*)&hbuf, (void*)&attn, (void*)&sc,
                  (void*)&out, (void*)&bar};
  hipLaunchCooperativeKernel((void*)k_persist, dim3(256), dim3(512), args, 0, stream);
}

// Round 6
// 4984.892 us; speedup vs baseline: 8.3076x; 1.0489x over previous
//
#include <hip/hip_runtime.h>
#include <hip/hip_fp16.h>

// B=32, T=128, Din=H=C=1024, S=128.
// R6: persistent cooperative kernel.
//  - two-level tree grid barrier (16 partitions x 16 blocks): parallel arrival
//    instead of R5's 256 serialized same-address RMWs (9.6us -> ~2us)
//  - phase A single-chunk staging (LDS 104.7KB; 1 block/CU anyway), 24 MFMAs
//    back-to-back, 2 fewer __syncthreads
//  - async preload (T14): x_{t+1}, h into regs before the step-end barrier;
//    only attn loaded after
//  - cross-block data via relaxed agent-scope atomics (coherent via L3)
//
// MFMA 16x16x32_f16 layout (guide §3, m89-verified):
//   A: lane l, elem j -> A[l&15][(l>>4)*8+j]
//   B: lane l, elem j -> B[(l>>4)*8+j][l&15]
//   D: lane l, reg  r -> D[(l>>4)*4+r][l&15]

typedef _Float16 f16x8 __attribute__((ext_vector_type(8)));
typedef float f32x4 __attribute__((ext_vector_type(4)));
typedef unsigned long long u64;

// ---- workspace layout (bytes) ----
#define OFF_XF16  ((size_t)0)           // [32][128][1024] f16     8,388,608
#define OFF_WP    ((size_t)8388608)     // [256][96][64][8] f16   25,165,824
#define OFF_WHP   ((size_t)33554432)    // [64][32][64][8] f16     2,097,152
#define OFF_BCAT  ((size_t)35651584)    // [1024][2048] f16        4,194,304
#define OFF_KPRE  ((size_t)39845888)    // [4096][1024] f16 row-major 8,388,608
#define OFF_CWT   ((size_t)48234496)    // [32][1024][128] f16     8,388,608
#define OFF_BIASR ((size_t)56623104)    // [4096] f32                 16,384
#define OFF_H2    ((size_t)56770560)    // [2][32][1024] f16         131,072
#define OFF_ATTN  ((size_t)56901632)    // [32][1024] f16             65,536
#define OFF_SC    ((size_t)56967168)    // [32][128] f32              16,384
#define OFF_BAR   ((size_t)56983552)    // [32] u32 barrier state (128B)

// ---- agent-scope coherent access helpers (bypass non-coherent L2) ----
__device__ __forceinline__ u64 aload64(const void* p) {
  return __hip_atomic_load((const u64*)p, __ATOMIC_RELAXED, __HIP_MEMORY_SCOPE_AGENT);
}
__device__ __forceinline__ void astore32(void* p, unsigned v) {
  __hip_atomic_store((unsigned*)p, v, __ATOMIC_RELAXED, __HIP_MEMORY_SCOPE_AGENT);
}
__device__ __forceinline__ void astore64(void* p, u64 v) {
  __hip_atomic_store((u64*)p, v, __ATOMIC_RELAXED, __HIP_MEMORY_SCOPE_AGENT);
}
__device__ __forceinline__ void astore16(void* p, unsigned short v) {
  __hip_atomic_store((unsigned short*)p, v, __ATOMIC_RELAXED, __HIP_MEMORY_SCOPE_AGENT);
}
__device__ __forceinline__ float4 aload128(const void* p) {
  float4 v;
  ((u64*)&v)[0] = aload64(p);
  ((u64*)&v)[1] = aload64((const char*)p + 8);
  return v;
}

// ---------------- one-time kernels ----------------

__global__ __launch_bounds__(256) void k_cvt_x(const float* __restrict__ x, __half* __restrict__ xf) {
  int i = blockIdx.x * 256 + threadIdx.x;
  float4 v = ((const float4*)x)[i];
  __half h4[4] = {__float2half(v.x), __float2half(v.y), __float2half(v.z), __float2half(v.w)};
  ((float2*)xf)[i] = *(float2*)h4;
}

__global__ __launch_bounds__(256) void k_build_bcat(const float* __restrict__ wq,
                                                    const float* __restrict__ wout,
                                                    __half* __restrict__ bcat) {
  int j = blockIdx.x * 256 + threadIdx.x;
  int c = blockIdx.y;
  float v = (j < 1024) ? wq[c * 1024 + j] : wout[(size_t)(j - 1024) * 2048 + c];
  bcat[c * 2048 + j] = __float2half(v);
}

// pack gate weights into MFMA A-fragment stream: wp[mt][ks][l][8]
// packed row r' = mt*16 + (l&15); original row = gate*1024 + u, r' = u*4+gate
__global__ __launch_bounds__(256) void k_pack_wp(const float* __restrict__ wih,
                                                 const float* __restrict__ whh,
                                                 __half* __restrict__ wpo) {
  int mt = blockIdx.x;
  int tid = threadIdx.x;
  int ks = blockIdx.y * 4 + (tid >> 6);
  int l = tid & 63;
  int rp = mt * 16 + (l & 15);
  int u = rp >> 2, g = rp & 3;
  int row = g * 1024 + u;
  int k = ks * 32 + (l >> 4) * 8;
  const float* src = (k < 2048) ? (wih + (size_t)row * 2048 + k)
                                : (whh + (size_t)row * 1024 + (k - 2048));
  float4 a = *(const float4*)src;
  float4 b = *(const float4*)(src + 4);
  __half o[8] = {__float2half(a.x), __float2half(a.y), __float2half(a.z), __float2half(a.w),
                 __float2half(b.x), __float2half(b.y), __float2half(b.z), __float2half(b.w)};
  *(float4*)(wpo + (((size_t)mt * 96 + ks) * 64 + l) * 8) = *(float4*)o;
}

__global__ __launch_bounds__(256) void k_pack_whp(const float* __restrict__ wout,
                                                  __half* __restrict__ wpo) {
  int nt = blockIdx.x;
  int tid = threadIdx.x;
  int ks = blockIdx.y * 4 + (tid >> 6);
  int l = tid & 63;
  int row = nt * 16 + (l & 15);
  int k = ks * 32 + (l >> 4) * 8;
  const float* src = wout + (size_t)row * 2048 + 1024 + k;
  float4 a = *(const float4*)src;
  float4 b = *(const float4*)(src + 4);
  __half o[8] = {__float2half(a.x), __float2half(a.y), __float2half(a.z), __float2half(a.w),
                 __float2half(b.x), __float2half(b.y), __float2half(b.z), __float2half(b.w)};
  *(float4*)(wpo + (((size_t)nt * 32 + ks) * 64 + l) * 8) = *(float4*)o;
}

__global__ __launch_bounds__(256) void k_bias_r(const float* __restrict__ bih,
                                                const float* __restrict__ bhh,
                                                float* __restrict__ biasr) {
  int i = blockIdx.x * 256 + threadIdx.x;
  int u = i >> 2, g = i & 3;
  biasr[i] = bih[g * 1024 + u] + bhh[g * 1024 + u];
}

// precompute GEMM: [4096 x 1024] fp32 @ [1024 x 2048] f16.
// n<1024 -> kpre[m][n] row-major ; n>=1024 -> CWT[b][n-1024][s] transposed
__global__ __launch_bounds__(256) void k_pregemm(const float* __restrict__ Af,
                                                 const __half* __restrict__ Bh,
                                                 __half* __restrict__ kpre,
                                                 __half* __restrict__ cwt) {
  __shared__ __half As[32][68];
  __shared__ __half Bs[32][72];
  int tid = threadIdx.x;
  int tx = tid & 15, ty = tid >> 4;
  int m0 = blockIdx.x * 64;
  int n0 = blockIdx.y * 64;
  float acc[4][4] = {};
  int arow = tid >> 2;
  int akq = (tid & 3) * 8;
  int brow = tid >> 3;
  int bcol = (tid & 7) * 8;

  for (int k0 = 0; k0 < 1024; k0 += 32) {
    const float* ap = Af + (size_t)(m0 + arow) * 1024 + k0 + akq;
    float4 a0 = *(const float4*)ap;
    float4 a1 = *(const float4*)(ap + 4);
    As[akq + 0][arow] = __float2half(a0.x);
    As[akq + 1][arow] = __float2half(a0.y);
    As[akq + 2][arow] = __float2half(a0.z);
    As[akq + 3][arow] = __float2half(a0.w);
    As[akq + 4][arow] = __float2half(a1.x);
    As[akq + 5][arow] = __float2half(a1.y);
    As[akq + 6][arow] = __float2half(a1.z);
    As[akq + 7][arow] = __float2half(a1.w);
    float4 bv = *(const float4*)(Bh + (size_t)(k0 + brow) * 2048 + n0 + bcol);
    *(float4*)&Bs[brow][bcol] = bv;
    __syncthreads();
#pragma unroll
    for (int k = 0; k < 32; ++k) {
      float2 avv = *(const float2*)&As[k][ty * 4];
      float2 bvv = *(const float2*)&Bs[k][tx * 4];
      const __half* ah = (const __half*)&avv;
      const __half* bh2 = (const __half*)&bvv;
#pragma unroll
      for (int i = 0; i < 4; ++i) {
        float af = __half2float(ah[i]);
#pragma unroll
        for (int j = 0; j < 4; ++j)
          acc[i][j] = fmaf(af, __half2float(bh2[j]), acc[i][j]);
      }
    }
    __syncthreads();
  }

  if (n0 < 1024) {
#pragma unroll
    for (int i = 0; i < 4; ++i) {
      int m = m0 + ty * 4 + i;
      __half o4[4] = {__float2half(acc[i][0]), __float2half(acc[i][1]),
                      __float2half(acc[i][2]), __float2half(acc[i][3])};
      *(float2*)&kpre[(size_t)m * 1024 + n0 + tx * 4] = *(float2*)o4;
    }
  } else {
    int b = m0 >> 7;
    int s0 = (m0 & 127) + ty * 4;
#pragma unroll
    for (int j = 0; j < 4; ++j) {
      int nl = (n0 - 1024) + tx * 4 + j;
      __half o4[4] = {__float2half(acc[0][j]), __float2half(acc[1][j]),
                      __float2half(acc[2][j]), __float2half(acc[3][j])};
      *(float2*)&cwt[((size_t)b * 1024 + nl) * 128 + s0] = *(float2*)o4;
    }
  }
}

// ---------------- two-level tree grid barrier ----------------
// bar[0..15]: partition counters (16 blocks each), bar[16]: partition-count,
// bar[17]: release generation, bar[18]: poison. Monotone generations, no reset.
// Data coherence: data uses agent-scope atomics; __syncthreads drains vmcnt
// before arrival.

__device__ __forceinline__ void gridbar(unsigned* bar, unsigned gen) {
  __syncthreads();
  if (threadIdx.x == 0) {
    if (__hip_atomic_load(&bar[18], __ATOMIC_RELAXED, __HIP_MEMORY_SCOPE_AGENT) == 0u) {
      unsigned a = __hip_atomic_fetch_add(&bar[blockIdx.x & 15], 1u,
                                          __ATOMIC_RELAXED, __HIP_MEMORY_SCOPE_AGENT);
      if (a == gen * 16u - 1u) {          // last of this partition for this gen
        unsigned g2 = __hip_atomic_fetch_add(&bar[16], 1u,
                                             __ATOMIC_RELAXED, __HIP_MEMORY_SCOPE_AGENT);
        if (g2 == gen * 16u - 1u)         // last partition
          __hip_atomic_store(&bar[17], gen, __ATOMIC_RELAXED, __HIP_MEMORY_SCOPE_AGENT);
      }
      unsigned spins = 0;
      while (__hip_atomic_load(&bar[17], __ATOMIC_RELAXED, __HIP_MEMORY_SCOPE_AGENT) < gen) {
        __builtin_amdgcn_s_sleep(1);
        if (++spins > 2000000u) {   // fail fast instead of hang
          __hip_atomic_store(&bar[18], 1u, __ATOMIC_RELAXED, __HIP_MEMORY_SCOPE_AGENT);
          break;
        }
      }
    }
    asm volatile("" ::: "memory");
  }
  __syncthreads();
}

// ---------------- persistent kernel ----------------
// LDS map (phases barrier-separated):
//  A: inp 16x6160B @0 (98,560) | redA @98,560 (6,144)   = 104,704
//  B: hs2 @0 (2,048)
//  C: hsl 16x2064B @0 (33,024) | al @33,024 (8,448) | redC @41,472 (7,168) | cx @48,640 (2,048)

__global__ __launch_bounds__(512, 2) void k_persist(
    const __half* __restrict__ xf, const f16x8* __restrict__ wp,
    const f16x8* __restrict__ whp, const __half* __restrict__ kpre,
    const __half* __restrict__ cwt, const float* __restrict__ biasr,
    const float* __restrict__ bout, __half* __restrict__ hbuf,
    __half* __restrict__ attn, float* __restrict__ scores,
    float* __restrict__ out, unsigned* __restrict__ bar) {
  __shared__ __align__(16) char smem[104704];
  int tid = threadIdx.x;
  int blk = blockIdx.x;
  int w = tid >> 6, l = tid & 63;
  int rl = l & 15, kg = l >> 4;

  // ---- phase A roles: block = (rblk 0..127 row-block) x (bh2 batch half)
  int rblk = blk >> 1, bh2 = blk & 1;
  int mh = w & 1, kq = w >> 1;       // wave: row-subtile, k-quarter
  int mtA = rblk * 2 + mh;           // packed 16-row tile id

  // register-resident gate weights: 24 frags (96 VGPR); wave kq covers
  // k-slices kq*24 .. kq*24+23 (of 96)
  f16x8 wa[24];
#pragma unroll
  for (int q = 0; q < 24; ++q)
    wa[q] = wp[((size_t)mtA * 96 + kq * 24 + q) * 64 + l];

  // phase C roles: blocks 0..127 active: (nt 0..63) x (bhc)
  bool actC = blk < 128;
  int nt = blk >> 1, bhc = blk & 1;
  f16x8 wc[4] = {};
  if (actC) {
#pragma unroll
    for (int q = 0; q < 4; ++q)
      wc[q] = whp[(((size_t)nt * 32) + w * 4 + q) * 64 + l];
  }

  float4 bvA = *(const float4*)&biasr[mtA * 16 + kg * 4];   // used by w<2
  float4 bo4 = {0, 0, 0, 0};
  if (actC) bo4 = *(const float4*)&bout[nt * 16 + kg * 4];  // used by w==0

  float creg = 0.f;   // cell state for (u = rblk*8+mh*4+kg, b = bh2*16+rl), w<2

  __half* inp = (__half*)smem;
  float* redA = (float*)(smem + 98560);
  __half* hs2 = (__half*)smem;
  __half* hsl = (__half*)smem;
  float* al   = (float*)(smem + 33024);
  float* redC = (float*)(smem + 41472);
  float* cx   = (float*)(smem + 48640);

  // phase B roles
  int bbB = blk >> 3, s0B = (blk & 7) * 16;

  // phase A staging roles: 16 rows (batches) x 32 stagers; u = c0+32j (16B units)
  int b0 = tid >> 5, c0 = tid & 31;
  int bbA = bh2 * 16 + b0;

  // T14 preload for t=0: x into regs, h=0
  float4 xv[4], hv4[4];
  {
    const __half* xrow = xf + ((size_t)bbA * 128 + 0) * 1024;
#pragma unroll
    for (int j = 0; j < 4; ++j) {
      xv[j] = *(const float4*)(xrow + (c0 + 32 * j) * 8);
      hv4[j].x = hv4[j].y = hv4[j].z = hv4[j].w = 0.f;
    }
  }

  for (int t = 0; t < 128; ++t) {
    int cur = t & 1;
    __half* hcur = hbuf + cur * 32768;

    // ======== phase A: gates MFMA + cell ========
    {
      char* drow = (char*)inp + b0 * 6160;
      // attn for this step (produced in prev phase C; zero at t=0)
      float4 av[4];
      if (t == 0) {
#pragma unroll
        for (int j = 0; j < 4; ++j) av[j].x = av[j].y = av[j].z = av[j].w = 0.f;
      } else {
        const __half* arow = attn + ((size_t)bbA << 10);
#pragma unroll
        for (int j = 0; j < 4; ++j)
          av[j] = aload128(arow + (c0 + 32 * j) * 8);   // coherent
      }
#pragma unroll
      for (int j = 0; j < 4; ++j) {
        *(float4*)(drow + (c0 + 32 * j) * 16) = xv[j];            // k 0..1023
        *(float4*)(drow + (128 + c0 + 32 * j) * 16) = av[j];      // k 1024..2047
        *(float4*)(drow + (256 + c0 + 32 * j) * 16) = hv4[j];     // k 2048..3071
      }
      __syncthreads();
      f32x4 acc0 = {0, 0, 0, 0}, acc1 = {0, 0, 0, 0};
      const char* brow = (const char*)inp + rl * 6160 + kg * 16;
#pragma unroll
      for (int q = 0; q < 24; q += 2) {
        f16x8 bf0 = *(const f16x8*)(brow + (kq * 24 + q) * 64);
        f16x8 bf1 = *(const f16x8*)(brow + (kq * 24 + q + 1) * 64);
        acc0 = __builtin_amdgcn_mfma_f32_16x16x32_f16(wa[q], bf0, acc0, 0, 0, 0);
        acc1 = __builtin_amdgcn_mfma_f32_16x16x32_f16(wa[q + 1], bf1, acc1, 0, 0, 0);
      }
      f32x4 acc;
      acc[0] = acc0[0] + acc1[0]; acc[1] = acc0[1] + acc1[1];
      acc[2] = acc0[2] + acc1[2]; acc[3] = acc0[3] + acc1[3];
      if (kq >= 1) *(f32x4*)&redA[(((kq - 1) * 2 + mh) * 64 + l) * 4] = acc;
      __syncthreads();
      if (w < 2) {   // kq==0, mh = w
#pragma unroll
        for (int p = 0; p < 3; ++p) {
          f32x4 o = *(f32x4*)&redA[((p * 2 + mh) * 64 + l) * 4];
          acc[0] += o[0]; acc[1] += o[1]; acc[2] += o[2]; acc[3] += o[3];
        }
        float gi = acc[0] + bvA.x;
        float gf = acc[1] + bvA.y;
        float gg = acc[2] + bvA.z;
        float go = acc[3] + bvA.w;
        float si = 1.f / (1.f + __expf(-gi));
        float sf = 1.f / (1.f + __expf(-gf));
        float so = 1.f / (1.f + __expf(-go));
        creg = sf * creg + si * tanhf(gg);
        int u = rblk * 8 + mh * 4 + kg;
        int b = bh2 * 16 + rl;
        __half hv = __float2half(so * tanhf(creg));
        astore16(&hcur[((size_t)b << 10) + u], *(unsigned short*)&hv);   // coherent
      }
    }
    gridbar(bar, 3 * t + 1);

    // ======== phase B: scores ========
    {
      if (tid < 128) {
        const __half* s = hcur + ((size_t)bbB << 10) + tid * 8;
        ((u64*)&hs2[tid * 8])[0] = aload64(s);          // coherent
        ((u64*)&hs2[tid * 8])[1] = aload64(s + 4);
      }
      __syncthreads();
      int sr = s0B + w * 2 + (l >> 5);
      int lk = l & 31;
      const __half* krow = kpre + ((size_t)(bbB * 128 + sr) << 10);
      float p = 0.f;
#pragma unroll
      for (int it = 0; it < 4; ++it) {
        int k = it * 256 + lk * 8;
        f16x8 kv = *(const f16x8*)(krow + k);
        f16x8 hv = *(const f16x8*)&hs2[k];
#pragma unroll
        for (int e = 0; e < 8; ++e) p = fmaf((float)kv[e], (float)hv[e], p);
      }
#pragma unroll
      for (int off = 16; off; off >>= 1) p += __shfl_xor(p, off);
      if (lk == 0) astore32(&scores[bbB * 128 + sr], __float_as_uint(p));   // coherent
    }
    gridbar(bar, 3 * t + 2);

    // ======== phase C: softmax + ctx + h-proj + tanh ========
    if (actC) {
      // stage h half (16 batches) — coherent reads
#pragma unroll
      for (int i2 = 0; i2 < 4; ++i2) {
        int f = i2 * 512 + tid;
        int b2 = f >> 7, u2 = f & 127;
        const __half* s = hcur + (((size_t)bhc * 16 + b2) << 10) + u2 * 8;
        char* d = (char*)hsl + b2 * 2064 + u2 * 16;
        ((u64*)d)[0] = aload64(s);
        ((u64*)d)[1] = aload64(s + 4);
      }
      // softmax: 32 lanes per batch — coherent score reads
      {
        int bl = tid >> 5, lj = tid & 31;
        const float* srow = scores + (bhc * 16 + bl) * 128;
        float4 sv = aload128(srow + lj * 4);
        float m = fmaxf(fmaxf(sv.x, sv.y), fmaxf(sv.z, sv.w));
#pragma unroll
        for (int off = 16; off; off >>= 1) m = fmaxf(m, __shfl_xor(m, off));
        float e0 = __expf(sv.x - m), e1 = __expf(sv.y - m);
        float e2 = __expf(sv.z - m), e3 = __expf(sv.w - m);
        float s = e0 + e1 + e2 + e3;
#pragma unroll
        for (int off = 16; off; off >>= 1) s += __shfl_xor(s, off);
        float inv = 1.f / s;
        float4 av2 = {e0 * inv, e1 * inv, e2 * inv, e3 * inv};
        *(float4*)&al[bl * 132 + lj * 4] = av2;
      }
      __syncthreads();
      // h-proj MFMA (K split across 8 waves)
      f32x4 acc2 = {0, 0, 0, 0};
      const char* brow2 = (const char*)hsl + rl * 2064 + kg * 16;
#pragma unroll
      for (int q = 0; q < 4; ++q) {
        f16x8 bf = *(const f16x8*)(brow2 + (w * 4 + q) * 64);
        acc2 = __builtin_amdgcn_mfma_f32_16x16x32_f16(wc[q], bf, acc2, 0, 0, 0);
      }
      // ctx partials: thread -> (n_l, b_l, s-half)
      {
        int nl2 = tid & 15, bl2 = (tid >> 4) & 15, sh = tid >> 8;
        const __half* crow = cwt + (((size_t)(bhc * 16 + bl2) << 10) + nt * 16 + nl2) * 128 + sh * 64;
        const float* arow2 = &al[bl2 * 132 + sh * 64];
        float pc = 0.f;
#pragma unroll
        for (int s2 = 0; s2 < 64; s2 += 8) {
          f16x8 cv = *(const f16x8*)(crow + s2);
#pragma unroll
          for (int e = 0; e < 8; ++e) pc = fmaf(arow2[s2 + e], (float)cv[e], pc);
        }
        cx[sh * 256 + bl2 * 16 + nl2] = pc;
      }
      if (w >= 1) *(f32x4*)&redC[((w - 1) * 64 + l) * 4] = acc2;
      __syncthreads();
      if (w == 0) {
#pragma unroll
        for (int p3 = 0; p3 < 7; ++p3) {
          f32x4 o = *(f32x4*)&redC[(p3 * 64 + l) * 4];
          acc2[0] += o[0]; acc2[1] += o[1]; acc2[2] += o[2]; acc2[3] += o[3];
        }
        int bfin = bhc * 16 + rl;
        int n0 = nt * 16 + kg * 4;
        float vo[4];
#pragma unroll
        for (int r = 0; r < 4; ++r) {
          float cv2 = cx[rl * 16 + kg * 4 + r] + cx[256 + rl * 16 + kg * 4 + r];
          float bb2 = (r == 0) ? bo4.x : (r == 1) ? bo4.y : (r == 2) ? bo4.z : bo4.w;
          vo[r] = tanhf(acc2[r] + cv2 + bb2);
        }
        __half o4[4] = {__float2half(vo[0]), __float2half(vo[1]),
                        __float2half(vo[2]), __float2half(vo[3])};
        astore64(&attn[((size_t)bfin << 10) + n0], *(u64*)o4);   // coherent
        float4 ov = {vo[0], vo[1], vo[2], vo[3]};
        *(float4*)&out[(((size_t)bfin * 128 + t) << 10) + n0] = ov;
      }
    }

    // T14 preload for t+1: x (plain, static) and h=hcur(t) (coherent, final
    // since before bar 3t+1). Only attn must wait for the barrier below.
    if (t < 127) {
      const __half* xrow = xf + ((size_t)bbA * 128 + (t + 1)) * 1024;
      const __half* hrow = hcur + ((size_t)bbA << 10);
#pragma unroll
      for (int j = 0; j < 4; ++j) {
        xv[j] = *(const float4*)(xrow + (c0 + 32 * j) * 8);
        hv4[j] = aload128(hrow + (c0 + 32 * j) * 8);
      }
    }
    gridbar(bar, 3 * t + 3);
  }
}

// ---------------- launcher ----------------

extern "C" void kernel_launch(void* const* d_in, const int* in_sizes, int n_in,
                              void* d_out, int out_size, void* d_ws, size_t ws_size,
                              hipStream_t stream) {
  const float* x    = (const float*)d_in[0];
  const float* ctxp = (const float*)d_in[1];
  const float* wih  = (const float*)d_in[2];
  const float* whh  = (const float*)d_in[3];
  const float* bih  = (const float*)d_in[4];
  const float* bhh  = (const float*)d_in[5];
  const float* wq   = (const float*)d_in[6];
  const float* wout = (const float*)d_in[7];
  const float* bo   = (const float*)d_in[8];
  float* out = (float*)d_out;
  char* ws = (char*)d_ws;

  __half* xf    = (__half*)(ws + OFF_XF16);
  __half* wpq   = (__half*)(ws + OFF_WP);
  __half* whpq  = (__half*)(ws + OFF_WHP);
  __half* bcat  = (__half*)(ws + OFF_BCAT);
  __half* kpre  = (__half*)(ws + OFF_KPRE);
  __half* cwt   = (__half*)(ws + OFF_CWT);
  float*  biasr = (float*)(ws + OFF_BIASR);
  __half* hbuf  = (__half*)(ws + OFF_H2);
  __half* attn  = (__half*)(ws + OFF_ATTN);
  float*  sc    = (float*)(ws + OFF_SC);
  unsigned* bar = (unsigned*)(ws + OFF_BAR);

  hipMemsetAsync(ws + OFF_BAR, 0, 128, stream);

  hipLaunchKernelGGL(k_cvt_x, dim3(4096), dim3(256), 0, stream, x, xf);
  hipLaunchKernelGGL(k_build_bcat, dim3(8, 1024), dim3(256), 0, stream, wq, wout, bcat);
  hipLaunchKernelGGL(k_pack_wp, dim3(256, 24), dim3(256), 0, stream, wih, whh, wpq);
  hipLaunchKernelGGL(k_pack_whp, dim3(64, 8), dim3(256), 0, stream, wout, whpq);
  hipLaunchKernelGGL(k_bias_r, dim3(16), dim3(256), 0, stream, bih, bhh, biasr);
  hipLaunchKernelGGL(k_pregemm, dim3(64, 32), dim3(256), 0, stream, ctxp, bcat, kpre, cwt);

  const f16x8* wpv = (const f16x8*)wpq;
  const f16x8* whpv = (const f16x8*)whpq;
  const __half* xfc = xf;
  const __half* kprec = kpre;
  const __half* cwtc = cwt;
  const float* biasrc = biasr;
  const float* boc = bo;
  void* args[] = {(void*)&xfc, (void*)&wpv, (void*)&whpv, (void*)&kprec, (void*)&cwtc,
                  (void*)&biasrc, (void*)&boc, (void*)&hbuf, (void*)&attn, (void*)&sc,
                  (void*)&out, (void*)&bar};
  hipLaunchCooperativeKernel((void*)k_persist, dim3(256), dim3(512), args, 0, stream);
}

// Round 7
// 2653.063 us; speedup vs baseline: 15.6093x; 1.8789x over previous
//
#include <hip/hip_runtime.h>
#include <hip/hip_fp16.h>

// B=32, T=128, Din=H=C=1024, S=128.
// R7: persistent cooperative kernel, TWO independent 128-block half-grids
// (split by batch half; never share data after weight load), each with a
// hierarchical padded barrier:
//  - every barrier word on its own 256B line (R6 bug: 16 "parallel" counters
//    shared ONE cache line -> L3 line-serialized, 9.7us/barrier)
//  - arrival: 8 partition counters x 16 blocks, leader bumps global counter
//  - release: leaders poll global release word (8 pollers), members poll
//    per-partition release (15 pollers) -> no 256-poller line storm
// Cross-block data via relaxed agent-scope atomics (coherent via L3).
//
// MFMA 16x16x32_f16 layout (guide §3, m89-verified):
//   A: lane l, elem j -> A[l&15][(l>>4)*8+j]
//   B: lane l, elem j -> B[(l>>4)*8+j][l&15]
//   D: lane l, reg  r -> D[(l>>4)*4+r][l&15]

typedef _Float16 f16x8 __attribute__((ext_vector_type(8)));
typedef float f32x4 __attribute__((ext_vector_type(4)));
typedef unsigned long long u64;

// ---- workspace layout (bytes) ----
#define OFF_XF16  ((size_t)0)           // [32][128][1024] f16     8,388,608
#define OFF_WP    ((size_t)8388608)     // [256][96][64][8] f16   25,165,824
#define OFF_WHP   ((size_t)33554432)    // [64][32][64][8] f16     2,097,152
#define OFF_BCAT  ((size_t)35651584)    // [1024][2048] f16        4,194,304
#define OFF_KPRE  ((size_t)39845888)    // [4096][1024] f16 row-major 8,388,608
#define OFF_CWT   ((size_t)48234496)    // [32][1024][128] f16     8,388,608
#define OFF_BIASR ((size_t)56623104)    // [4096] f32                 16,384
#define OFF_H2    ((size_t)56770560)    // [2][32][1024] f16         131,072
#define OFF_ATTN  ((size_t)56901632)    // [32][1024] f16             65,536
#define OFF_SC    ((size_t)56967168)    // [32][128] f32              16,384
#define OFF_BAR   ((size_t)56983552)    // 32 KB barrier state (2 halves x 16KB)

// ---- agent-scope coherent access helpers (bypass non-coherent L2) ----
__device__ __forceinline__ u64 aload64(const void* p) {
  return __hip_atomic_load((const u64*)p, __ATOMIC_RELAXED, __HIP_MEMORY_SCOPE_AGENT);
}
__device__ __forceinline__ unsigned aload32u(const unsigned* p) {
  return __hip_atomic_load(p, __ATOMIC_RELAXED, __HIP_MEMORY_SCOPE_AGENT);
}
__device__ __forceinline__ void astore32(void* p, unsigned v) {
  __hip_atomic_store((unsigned*)p, v, __ATOMIC_RELAXED, __HIP_MEMORY_SCOPE_AGENT);
}
__device__ __forceinline__ void astore64(void* p, u64 v) {
  __hip_atomic_store((u64*)p, v, __ATOMIC_RELAXED, __HIP_MEMORY_SCOPE_AGENT);
}
__device__ __forceinline__ void astore16(void* p, unsigned short v) {
  __hip_atomic_store((unsigned short*)p, v, __ATOMIC_RELAXED, __HIP_MEMORY_SCOPE_AGENT);
}
__device__ __forceinline__ float4 aload128(const void* p) {
  float4 v;
  ((u64*)&v)[0] = aload64(p);
  ((u64*)&v)[1] = aload64((const char*)p + 8);
  return v;
}

// ---------------- one-time kernels ----------------

__global__ __launch_bounds__(256) void k_cvt_x(const float* __restrict__ x, __half* __restrict__ xf) {
  int i = blockIdx.x * 256 + threadIdx.x;
  float4 v = ((const float4*)x)[i];
  __half h4[4] = {__float2half(v.x), __float2half(v.y), __float2half(v.z), __float2half(v.w)};
  ((float2*)xf)[i] = *(float2*)h4;
}

__global__ __launch_bounds__(256) void k_build_bcat(const float* __restrict__ wq,
                                                    const float* __restrict__ wout,
                                                    __half* __restrict__ bcat) {
  int j = blockIdx.x * 256 + threadIdx.x;
  int c = blockIdx.y;
  float v = (j < 1024) ? wq[c * 1024 + j] : wout[(size_t)(j - 1024) * 2048 + c];
  bcat[c * 2048 + j] = __float2half(v);
}

// pack gate weights into MFMA A-fragment stream: wp[mt][ks][l][8]
// packed row r' = mt*16 + (l&15); original row = gate*1024 + u, r' = u*4+gate
__global__ __launch_bounds__(256) void k_pack_wp(const float* __restrict__ wih,
                                                 const float* __restrict__ whh,
                                                 __half* __restrict__ wpo) {
  int mt = blockIdx.x;
  int tid = threadIdx.x;
  int ks = blockIdx.y * 4 + (tid >> 6);
  int l = tid & 63;
  int rp = mt * 16 + (l & 15);
  int u = rp >> 2, g = rp & 3;
  int row = g * 1024 + u;
  int k = ks * 32 + (l >> 4) * 8;
  const float* src = (k < 2048) ? (wih + (size_t)row * 2048 + k)
                                : (whh + (size_t)row * 1024 + (k - 2048));
  float4 a = *(const float4*)src;
  float4 b = *(const float4*)(src + 4);
  __half o[8] = {__float2half(a.x), __float2half(a.y), __float2half(a.z), __float2half(a.w),
                 __float2half(b.x), __float2half(b.y), __float2half(b.z), __float2half(b.w)};
  *(float4*)(wpo + (((size_t)mt * 96 + ks) * 64 + l) * 8) = *(float4*)o;
}

__global__ __launch_bounds__(256) void k_pack_whp(const float* __restrict__ wout,
                                                  __half* __restrict__ wpo) {
  int nt = blockIdx.x;
  int tid = threadIdx.x;
  int ks = blockIdx.y * 4 + (tid >> 6);
  int l = tid & 63;
  int row = nt * 16 + (l & 15);
  int k = ks * 32 + (l >> 4) * 8;
  const float* src = wout + (size_t)row * 2048 + 1024 + k;
  float4 a = *(const float4*)src;
  float4 b = *(const float4*)(src + 4);
  __half o[8] = {__float2half(a.x), __float2half(a.y), __float2half(a.z), __float2half(a.w),
                 __float2half(b.x), __float2half(b.y), __float2half(b.z), __float2half(b.w)};
  *(float4*)(wpo + (((size_t)nt * 32 + ks) * 64 + l) * 8) = *(float4*)o;
}

__global__ __launch_bounds__(256) void k_bias_r(const float* __restrict__ bih,
                                                const float* __restrict__ bhh,
                                                float* __restrict__ biasr) {
  int i = blockIdx.x * 256 + threadIdx.x;
  int u = i >> 2, g = i & 3;
  biasr[i] = bih[g * 1024 + u] + bhh[g * 1024 + u];
}

// precompute GEMM: [4096 x 1024] fp32 @ [1024 x 2048] f16.
// n<1024 -> kpre[m][n] row-major ; n>=1024 -> CWT[b][n-1024][s] transposed
__global__ __launch_bounds__(256) void k_pregemm(const float* __restrict__ Af,
                                                 const __half* __restrict__ Bh,
                                                 __half* __restrict__ kpre,
                                                 __half* __restrict__ cwt) {
  __shared__ __half As[32][68];
  __shared__ __half Bs[32][72];
  int tid = threadIdx.x;
  int tx = tid & 15, ty = tid >> 4;
  int m0 = blockIdx.x * 64;
  int n0 = blockIdx.y * 64;
  float acc[4][4] = {};
  int arow = tid >> 2;
  int akq = (tid & 3) * 8;
  int brow = tid >> 3;
  int bcol = (tid & 7) * 8;

  for (int k0 = 0; k0 < 1024; k0 += 32) {
    const float* ap = Af + (size_t)(m0 + arow) * 1024 + k0 + akq;
    float4 a0 = *(const float4*)ap;
    float4 a1 = *(const float4*)(ap + 4);
    As[akq + 0][arow] = __float2half(a0.x);
    As[akq + 1][arow] = __float2half(a0.y);
    As[akq + 2][arow] = __float2half(a0.z);
    As[akq + 3][arow] = __float2half(a0.w);
    As[akq + 4][arow] = __float2half(a1.x);
    As[akq + 5][arow] = __float2half(a1.y);
    As[akq + 6][arow] = __float2half(a1.z);
    As[akq + 7][arow] = __float2half(a1.w);
    float4 bv = *(const float4*)(Bh + (size_t)(k0 + brow) * 2048 + n0 + bcol);
    *(float4*)&Bs[brow][bcol] = bv;
    __syncthreads();
#pragma unroll
    for (int k = 0; k < 32; ++k) {
      float2 avv = *(const float2*)&As[k][ty * 4];
      float2 bvv = *(const float2*)&Bs[k][tx * 4];
      const __half* ah = (const __half*)&avv;
      const __half* bh2 = (const __half*)&bvv;
#pragma unroll
      for (int i = 0; i < 4; ++i) {
        float af = __half2float(ah[i]);
#pragma unroll
        for (int j = 0; j < 4; ++j)
          acc[i][j] = fmaf(af, __half2float(bh2[j]), acc[i][j]);
      }
    }
    __syncthreads();
  }

  if (n0 < 1024) {
#pragma unroll
    for (int i = 0; i < 4; ++i) {
      int m = m0 + ty * 4 + i;
      __half o4[4] = {__float2half(acc[i][0]), __float2half(acc[i][1]),
                      __float2half(acc[i][2]), __float2half(acc[i][3])};
      *(float2*)&kpre[(size_t)m * 1024 + n0 + tx * 4] = *(float2*)o4;
    }
  } else {
    int b = m0 >> 7;
    int s0 = (m0 & 127) + ty * 4;
#pragma unroll
    for (int j = 0; j < 4; ++j) {
      int nl = (n0 - 1024) + tx * 4 + j;
      __half o4[4] = {__float2half(acc[0][j]), __float2half(acc[1][j]),
                      __float2half(acc[2][j]), __float2half(acc[3][j])};
      *(float2*)&cwt[((size_t)b * 1024 + nl) * 128 + s0] = *(float2*)o4;
    }
  }
}

// ---------------- hierarchical padded half-barrier ----------------
// Per half (128 blocks): B = bar + half*4096 (u32). Every word on its own
// 256B line:
//   part_ctr[p] = B[p*64]        p=0..7   (16 blocks each)
//   glob_ctr    = B[512]
//   glob_rel    = B[576]
//   part_rel[p] = B[1024+p*64]
//   poison      = B[2048]
// Monotone generations, no resets.

__device__ __forceinline__ void halfbar(unsigned* B, int hblk, unsigned gen) {
  __syncthreads();
  if (threadIdx.x == 0) {
    int p = hblk >> 4;
    unsigned a = __hip_atomic_fetch_add(&B[p * 64], 1u,
                                        __ATOMIC_RELAXED, __HIP_MEMORY_SCOPE_AGENT);
    if (a == gen * 16u - 1u) {               // last of partition for this gen
      unsigned g2 = __hip_atomic_fetch_add(&B[512], 1u,
                                           __ATOMIC_RELAXED, __HIP_MEMORY_SCOPE_AGENT);
      if (g2 == gen * 8u - 1u)               // last partition
        astore32(&B[576], gen);
    }
    unsigned spins = 0;
    if ((hblk & 15) == 0) {                  // partition leader
      while (aload32u(&B[576]) < gen) {
        __builtin_amdgcn_s_sleep(2);
        if ((++spins & 255u) == 0u) {
          if (aload32u(&B[2048]) != 0u) break;
          if (spins > 3000000u) { astore32(&B[2048], 1u); break; }
        }
      }
      astore32(&B[1024 + p * 64], gen);      // propagate to members
    } else {
      while (aload32u(&B[1024 + p * 64]) < gen) {
        __builtin_amdgcn_s_sleep(2);
        if ((++spins & 255u) == 0u) {
          if (aload32u(&B[2048]) != 0u) break;
          if (spins > 3000000u) { astore32(&B[2048], 1u); break; }
        }
      }
    }
    asm volatile("" ::: "memory");
  }
  __syncthreads();
}

// ---------------- persistent kernel ----------------
// Two independent half-grids: half = blk>>7 (batches half*16..half*16+15),
// hblk = blk&127. LDS map (phases barrier-separated):
//  A: inp 16x6160B @0 (98,560) | redA @98,560 (6,144)   = 104,704
//  B: hs2 @0 (2,048)
//  C: hsl 16x2064B @0 (33,024) | al @33,024 (8,448) | redC @41,472 (7,168) | cx @48,640 (2,048)

__global__ __launch_bounds__(512, 2) void k_persist(
    const __half* __restrict__ xf, const f16x8* __restrict__ wp,
    const f16x8* __restrict__ whp, const __half* __restrict__ kpre,
    const __half* __restrict__ cwt, const float* __restrict__ biasr,
    const float* __restrict__ bout, __half* __restrict__ hbuf,
    __half* __restrict__ attn, float* __restrict__ scores,
    float* __restrict__ out, unsigned* __restrict__ bar) {
  __shared__ __align__(16) char smem[104704];
  int tid = threadIdx.x;
  int blk = blockIdx.x;
  int half = blk >> 7, hblk = blk & 127;
  unsigned* Bbar = bar + half * 4096;
  int w = tid >> 6, l = tid & 63;
  int rl = l & 15, kg = l >> 4;

  // ---- phase A roles: rblk = hblk (row-block of 8 u), batch half = half
  int rblk = hblk, bh2 = half;
  int mh = w & 1, kq = w >> 1;       // wave: row-subtile, k-quarter
  int mtA = rblk * 2 + mh;           // packed 16-row tile id

  // register-resident gate weights: 24 frags (96 VGPR); wave kq covers
  // k-slices kq*24 .. kq*24+23 (of 96)
  f16x8 wa[24];
#pragma unroll
  for (int q = 0; q < 24; ++q)
    wa[q] = wp[((size_t)mtA * 96 + kq * 24 + q) * 64 + l];

  // phase C roles: nt pairs duplicate (hblk even/odd), bhc = half
  int nt = hblk >> 1, bhc = half;
  f16x8 wc[4];
#pragma unroll
  for (int q = 0; q < 4; ++q)
    wc[q] = whp[(((size_t)nt * 32) + w * 4 + q) * 64 + l];

  float4 bvA = *(const float4*)&biasr[mtA * 16 + kg * 4];   // used by w<2
  float4 bo4 = *(const float4*)&bout[nt * 16 + kg * 4];     // used by w==0

  float creg = 0.f;   // cell state for (u = rblk*8+mh*4+kg, b = bh2*16+rl), w<2

  __half* inp = (__half*)smem;
  float* redA = (float*)(smem + 98560);
  __half* hs2 = (__half*)smem;
  __half* hsl = (__half*)smem;
  float* al   = (float*)(smem + 33024);
  float* redC = (float*)(smem + 41472);
  float* cx   = (float*)(smem + 48640);

  // phase B roles: 128 blocks cover 16 batches x 8 s-groups
  int bbB = half * 16 + (hblk >> 3), s0B = (hblk & 7) * 16;

  // phase A staging roles: 16 rows (batches) x 32 stagers; u = c0+32j (16B units)
  int b0 = tid >> 5, c0 = tid & 31;
  int bbA = bh2 * 16 + b0;

  // T14 preload for t=0: x into regs, h=0
  float4 xv[4], hv4[4];
  {
    const __half* xrow = xf + ((size_t)bbA * 128 + 0) * 1024;
#pragma unroll
    for (int j = 0; j < 4; ++j) {
      xv[j] = *(const float4*)(xrow + (c0 + 32 * j) * 8);
      hv4[j].x = hv4[j].y = hv4[j].z = hv4[j].w = 0.f;
    }
  }

  for (int t = 0; t < 128; ++t) {
    int cur = t & 1;
    __half* hcur = hbuf + cur * 32768;

    // ======== phase A: gates MFMA + cell ========
    {
      char* drow = (char*)inp + b0 * 6160;
      // attn for this step (produced in prev phase C; zero at t=0)
      float4 av[4];
      if (t == 0) {
#pragma unroll
        for (int j = 0; j < 4; ++j) av[j].x = av[j].y = av[j].z = av[j].w = 0.f;
      } else {
        const __half* arow = attn + ((size_t)bbA << 10);
#pragma unroll
        for (int j = 0; j < 4; ++j)
          av[j] = aload128(arow + (c0 + 32 * j) * 8);   // coherent
      }
#pragma unroll
      for (int j = 0; j < 4; ++j) {
        *(float4*)(drow + (c0 + 32 * j) * 16) = xv[j];            // k 0..1023
        *(float4*)(drow + (128 + c0 + 32 * j) * 16) = av[j];      // k 1024..2047
        *(float4*)(drow + (256 + c0 + 32 * j) * 16) = hv4[j];     // k 2048..3071
      }
      __syncthreads();
      f32x4 acc0 = {0, 0, 0, 0}, acc1 = {0, 0, 0, 0};
      const char* brow = (const char*)inp + rl * 6160 + kg * 16;
#pragma unroll
      for (int q = 0; q < 24; q += 2) {
        f16x8 bf0 = *(const f16x8*)(brow + (kq * 24 + q) * 64);
        f16x8 bf1 = *(const f16x8*)(brow + (kq * 24 + q + 1) * 64);
        acc0 = __builtin_amdgcn_mfma_f32_16x16x32_f16(wa[q], bf0, acc0, 0, 0, 0);
        acc1 = __builtin_amdgcn_mfma_f32_16x16x32_f16(wa[q + 1], bf1, acc1, 0, 0, 0);
      }
      f32x4 acc;
      acc[0] = acc0[0] + acc1[0]; acc[1] = acc0[1] + acc1[1];
      acc[2] = acc0[2] + acc1[2]; acc[3] = acc0[3] + acc1[3];
      if (kq >= 1) *(f32x4*)&redA[(((kq - 1) * 2 + mh) * 64 + l) * 4] = acc;
      __syncthreads();
      if (w < 2) {   // kq==0, mh = w
#pragma unroll
        for (int p = 0; p < 3; ++p) {
          f32x4 o = *(f32x4*)&redA[((p * 2 + mh) * 64 + l) * 4];
          acc[0] += o[0]; acc[1] += o[1]; acc[2] += o[2]; acc[3] += o[3];
        }
        float gi = acc[0] + bvA.x;
        float gf = acc[1] + bvA.y;
        float gg = acc[2] + bvA.z;
        float go = acc[3] + bvA.w;
        float si = 1.f / (1.f + __expf(-gi));
        float sf = 1.f / (1.f + __expf(-gf));
        float so = 1.f / (1.f + __expf(-go));
        creg = sf * creg + si * tanhf(gg);
        int u = rblk * 8 + mh * 4 + kg;
        int b = bh2 * 16 + rl;
        __half hv = __float2half(so * tanhf(creg));
        astore16(&hcur[((size_t)b << 10) + u], *(unsigned short*)&hv);   // coherent
      }
    }
    halfbar(Bbar, hblk, 3 * t + 1);

    // ======== phase B: scores ========
    {
      if (tid < 128) {
        const __half* s = hcur + ((size_t)bbB << 10) + tid * 8;
        ((u64*)&hs2[tid * 8])[0] = aload64(s);          // coherent
        ((u64*)&hs2[tid * 8])[1] = aload64(s + 4);
      }
      __syncthreads();
      int sr = s0B + w * 2 + (l >> 5);
      int lk = l & 31;
      const __half* krow = kpre + ((size_t)(bbB * 128 + sr) << 10);
      float p = 0.f;
#pragma unroll
      for (int it = 0; it < 4; ++it) {
        int k = it * 256 + lk * 8;
        f16x8 kv = *(const f16x8*)(krow + k);
        f16x8 hv = *(const f16x8*)&hs2[k];
#pragma unroll
        for (int e = 0; e < 8; ++e) p = fmaf((float)kv[e], (float)hv[e], p);
      }
#pragma unroll
      for (int off = 16; off; off >>= 1) p += __shfl_xor(p, off);
      if (lk == 0) astore32(&scores[bbB * 128 + sr], __float_as_uint(p));   // coherent
    }
    halfbar(Bbar, hblk, 3 * t + 2);

    // ======== phase C: softmax + ctx + h-proj + tanh ========
    {
      // stage h half (16 batches) — coherent reads
#pragma unroll
      for (int i2 = 0; i2 < 4; ++i2) {
        int f = i2 * 512 + tid;
        int b2 = f >> 7, u2 = f & 127;
        const __half* s = hcur + (((size_t)bhc * 16 + b2) << 10) + u2 * 8;
        char* d = (char*)hsl + b2 * 2064 + u2 * 16;
        ((u64*)d)[0] = aload64(s);
        ((u64*)d)[1] = aload64(s + 4);
      }
      // softmax: 32 lanes per batch — coherent score reads
      {
        int bl = tid >> 5, lj = tid & 31;
        const float* srow = scores + (bhc * 16 + bl) * 128;
        float4 sv = aload128(srow + lj * 4);
        float m = fmaxf(fmaxf(sv.x, sv.y), fmaxf(sv.z, sv.w));
#pragma unroll
        for (int off = 16; off; off >>= 1) m = fmaxf(m, __shfl_xor(m, off));
        float e0 = __expf(sv.x - m), e1 = __expf(sv.y - m);
        float e2 = __expf(sv.z - m), e3 = __expf(sv.w - m);
        float s = e0 + e1 + e2 + e3;
#pragma unroll
        for (int off = 16; off; off >>= 1) s += __shfl_xor(s, off);
        float inv = 1.f / s;
        float4 av2 = {e0 * inv, e1 * inv, e2 * inv, e3 * inv};
        *(float4*)&al[bl * 132 + lj * 4] = av2;
      }
      __syncthreads();
      // h-proj MFMA (K split across 8 waves)
      f32x4 acc2 = {0, 0, 0, 0};
      const char* brow2 = (const char*)hsl + rl * 2064 + kg * 16;
#pragma unroll
      for (int q = 0; q < 4; ++q) {
        f16x8 bf = *(const f16x8*)(brow2 + (w * 4 + q) * 64);
        acc2 = __builtin_amdgcn_mfma_f32_16x16x32_f16(wc[q], bf, acc2, 0, 0, 0);
      }
      // ctx partials: thread -> (n_l, b_l, s-half)
      {
        int nl2 = tid & 15, bl2 = (tid >> 4) & 15, sh = tid >> 8;
        const __half* crow = cwt + (((size_t)(bhc * 16 + bl2) << 10) + nt * 16 + nl2) * 128 + sh * 64;
        const float* arow2 = &al[bl2 * 132 + sh * 64];
        float pc = 0.f;
#pragma unroll
        for (int s2 = 0; s2 < 64; s2 += 8) {
          f16x8 cv = *(const f16x8*)(crow + s2);
#pragma unroll
          for (int e = 0; e < 8; ++e) pc = fmaf(arow2[s2 + e], (float)cv[e], pc);
        }
        cx[sh * 256 + bl2 * 16 + nl2] = pc;
      }
      if (w >= 1) *(f32x4*)&redC[((w - 1) * 64 + l) * 4] = acc2;
      __syncthreads();
      if (w == 0) {
#pragma unroll
        for (int p3 = 0; p3 < 7; ++p3) {
          f32x4 o = *(f32x4*)&redC[(p3 * 64 + l) * 4];
          acc2[0] += o[0]; acc2[1] += o[1]; acc2[2] += o[2]; acc2[3] += o[3];
        }
        int bfin = bhc * 16 + rl;
        int n0 = nt * 16 + kg * 4;
        float vo[4];
#pragma unroll
        for (int r = 0; r < 4; ++r) {
          float cv2 = cx[rl * 16 + kg * 4 + r] + cx[256 + rl * 16 + kg * 4 + r];
          float bb2 = (r == 0) ? bo4.x : (r == 1) ? bo4.y : (r == 2) ? bo4.z : bo4.w;
          vo[r] = tanhf(acc2[r] + cv2 + bb2);
        }
        __half o4[4] = {__float2half(vo[0]), __float2half(vo[1]),
                        __float2half(vo[2]), __float2half(vo[3])};
        astore64(&attn[((size_t)bfin << 10) + n0], *(u64*)o4);   // coherent (pair writes same value)
        float4 ov = {vo[0], vo[1], vo[2], vo[3]};
        *(float4*)&out[(((size_t)bfin * 128 + t) << 10) + n0] = ov;
      }
    }

    // T14 preload for t+1: x (plain, static) and h=hcur(t) (coherent, final
    // since before bar 3t+1). Only attn must wait for the barrier below.
    if (t < 127) {
      const __half* xrow = xf + ((size_t)bbA * 128 + (t + 1)) * 1024;
      const __half* hrow = hcur + ((size_t)bbA << 10);
#pragma unroll
      for (int j = 0; j < 4; ++j) {
        xv[j] = *(const float4*)(xrow + (c0 + 32 * j) * 8);
        hv4[j] = aload128(hrow + (c0 + 32 * j) * 8);
      }
    }
    halfbar(Bbar, hblk, 3 * t + 3);
  }
}

// ---------------- launcher ----------------

extern "C" void kernel_launch(void* const* d_in, const int* in_sizes, int n_in,
                              void* d_out, int out_size, void* d_ws, size_t ws_size,
                              hipStream_t stream) {
  const float* x    = (const float*)d_in[0];
  const float* ctxp = (const float*)d_in[1];
  const float* wih  = (const float*)d_in[2];
  const float* whh  = (const float*)d_in[3];
  const float* bih  = (const float*)d_in[4];
  const float* bhh  = (const float*)d_in[5];
  const float* wq   = (const float*)d_in[6];
  const float* wout = (const float*)d_in[7];
  const float* bo   = (const float*)d_in[8];
  float* out = (float*)d_out;
  char* ws = (char*)d_ws;

  __half* xf    = (__half*)(ws + OFF_XF16);
  __half* wpq   = (__half*)(ws + OFF_WP);
  __half* whpq  = (__half*)(ws + OFF_WHP);
  __half* bcat  = (__half*)(ws + OFF_BCAT);
  __half* kpre  = (__half*)(ws + OFF_KPRE);
  __half* cwt   = (__half*)(ws + OFF_CWT);
  float*  biasr = (float*)(ws + OFF_BIASR);
  __half* hbuf  = (__half*)(ws + OFF_H2);
  __half* attn  = (__half*)(ws + OFF_ATTN);
  float*  sc    = (float*)(ws + OFF_SC);
  unsigned* bar = (unsigned*)(ws + OFF_BAR);

  hipMemsetAsync(ws + OFF_BAR, 0, 32768, stream);

  hipLaunchKernelGGL(k_cvt_x, dim3(4096), dim3(256), 0, stream, x, xf);
  hipLaunchKernelGGL(k_build_bcat, dim3(8, 1024), dim3(256), 0, stream, wq, wout, bcat);
  hipLaunchKernelGGL(k_pack_wp, dim3(256, 24), dim3(256), 0, stream, wih, whh, wpq);
  hipLaunchKernelGGL(k_pack_whp, dim3(64, 8), dim3(256), 0, stream, wout, whpq);
  hipLaunchKernelGGL(k_bias_r, dim3(16), dim3(256), 0, stream, bih, bhh, biasr);
  hipLaunchKernelGGL(k_pregemm, dim3(64, 32), dim3(256), 0, stream, ctxp, bcat, kpre, cwt);

  const f16x8* wpv = (const f16x8*)wpq;
  const f16x8* whpv = (const f16x8*)whpq;
  const __half* xfc = xf;
  const __half* kprec = kpre;
  const __half* cwtc = cwt;
  const float* biasrc = biasr;
  const float* boc = bo;
  void* args[] = {(void*)&xfc, (void*)&wpv, (void*)&whpv, (void*)&kprec, (void*)&cwtc,
                  (void*)&biasrc, (void*)&boc, (void*)&hbuf, (void*)&attn, (void*)&sc,
                  (void*)&out, (void*)&bar};
  hipLaunchCooperativeKernel((void*)k_persist, dim3(256), dim3(512), args, 0, stream);
}

// Round 8
// 2370.583 us; speedup vs baseline: 17.4693x; 1.1192x over previous
//
#include <hip/hip_runtime.h>
#include <hip/hip_fp16.h>

// B=32, T=128, Din=H=C=1024, S=128.
// R8: persistent cooperative kernel, two independent 128-block half-grids.
//  vs R7: (1) flat barrier release (last arriver writes all 8 partition
//  release lines; no leader-poll hop); (2) kpre rows + cwt slices register-
//  resident (loop-invariant); (3) h-proj MFMA moved to phase B, h staged once,
//  redC persists in LDS across the barrier into phase C; (4) MFMA pregemm.
//
// MFMA 16x16x32_f16 layout (guide §3, m89-verified):
//   A: lane l, elem j -> A[l&15][(l>>4)*8+j]
//   B: lane l, elem j -> B[(l>>4)*8+j][l&15]
//   D: lane l, reg  r -> D[(l>>4)*4+r][l&15]

typedef _Float16 f16x8 __attribute__((ext_vector_type(8)));
typedef float f32x4 __attribute__((ext_vector_type(4)));
typedef unsigned long long u64;

// ---- workspace layout (bytes) ----
#define OFF_XF16  ((size_t)0)           // [32][128][1024] f16     8,388,608
#define OFF_WP    ((size_t)8388608)     // [256][96][64][8] f16   25,165,824
#define OFF_WHP   ((size_t)33554432)    // [64][32][64][8] f16     2,097,152
#define OFF_BCAT  ((size_t)35651584)    // [1024][2048] f16        4,194,304
#define OFF_KPRE  ((size_t)39845888)    // [4096][1024] f16 row-major 8,388,608
#define OFF_CWT   ((size_t)48234496)    // [32][1024][128] f16     8,388,608
#define OFF_BIASR ((size_t)56623104)    // [4096] f32                 16,384
#define OFF_H2    ((size_t)56770560)    // [2][32][1024] f16         131,072
#define OFF_ATTN  ((size_t)56901632)    // [32][1024] f16             65,536
#define OFF_SC    ((size_t)56967168)    // [32][128] f32              16,384
#define OFF_BAR   ((size_t)56983552)    // 32 KB barrier state (2 halves x 16KB)

// ---- agent-scope coherent access helpers (bypass non-coherent L2) ----
__device__ __forceinline__ u64 aload64(const void* p) {
  return __hip_atomic_load((const u64*)p, __ATOMIC_RELAXED, __HIP_MEMORY_SCOPE_AGENT);
}
__device__ __forceinline__ unsigned aload32u(const unsigned* p) {
  return __hip_atomic_load(p, __ATOMIC_RELAXED, __HIP_MEMORY_SCOPE_AGENT);
}
__device__ __forceinline__ void astore32(void* p, unsigned v) {
  __hip_atomic_store((unsigned*)p, v, __ATOMIC_RELAXED, __HIP_MEMORY_SCOPE_AGENT);
}
__device__ __forceinline__ void astore64(void* p, u64 v) {
  __hip_atomic_store((u64*)p, v, __ATOMIC_RELAXED, __HIP_MEMORY_SCOPE_AGENT);
}
__device__ __forceinline__ void astore16(void* p, unsigned short v) {
  __hip_atomic_store((unsigned short*)p, v, __ATOMIC_RELAXED, __HIP_MEMORY_SCOPE_AGENT);
}
__device__ __forceinline__ float4 aload128(const void* p) {
  float4 v;
  ((u64*)&v)[0] = aload64(p);
  ((u64*)&v)[1] = aload64((const char*)p + 8);
  return v;
}

// ---------------- one-time kernels ----------------

__global__ __launch_bounds__(256) void k_cvt_x(const float* __restrict__ x, __half* __restrict__ xf) {
  int i = blockIdx.x * 256 + threadIdx.x;
  float4 v = ((const float4*)x)[i];
  __half h4[4] = {__float2half(v.x), __float2half(v.y), __float2half(v.z), __float2half(v.w)};
  ((float2*)xf)[i] = *(float2*)h4;
}

__global__ __launch_bounds__(256) void k_build_bcat(const float* __restrict__ wq,
                                                    const float* __restrict__ wout,
                                                    __half* __restrict__ bcat) {
  int j = blockIdx.x * 256 + threadIdx.x;
  int c = blockIdx.y;
  float v = (j < 1024) ? wq[c * 1024 + j] : wout[(size_t)(j - 1024) * 2048 + c];
  bcat[c * 2048 + j] = __float2half(v);
}

// pack gate weights into MFMA A-fragment stream: wp[mt][ks][l][8]
// packed row r' = mt*16 + (l&15); original row = gate*1024 + u, r' = u*4+gate
__global__ __launch_bounds__(256) void k_pack_wp(const float* __restrict__ wih,
                                                 const float* __restrict__ whh,
                                                 __half* __restrict__ wpo) {
  int mt = blockIdx.x;
  int tid = threadIdx.x;
  int ks = blockIdx.y * 4 + (tid >> 6);
  int l = tid & 63;
  int rp = mt * 16 + (l & 15);
  int u = rp >> 2, g = rp & 3;
  int row = g * 1024 + u;
  int k = ks * 32 + (l >> 4) * 8;
  const float* src = (k < 2048) ? (wih + (size_t)row * 2048 + k)
                                : (whh + (size_t)row * 1024 + (k - 2048));
  float4 a = *(const float4*)src;
  float4 b = *(const float4*)(src + 4);
  __half o[8] = {__float2half(a.x), __float2half(a.y), __float2half(a.z), __float2half(a.w),
                 __float2half(b.x), __float2half(b.y), __float2half(b.z), __float2half(b.w)};
  *(float4*)(wpo + (((size_t)mt * 96 + ks) * 64 + l) * 8) = *(float4*)o;
}

__global__ __launch_bounds__(256) void k_pack_whp(const float* __restrict__ wout,
                                                  __half* __restrict__ wpo) {
  int nt = blockIdx.x;
  int tid = threadIdx.x;
  int ks = blockIdx.y * 4 + (tid >> 6);
  int l = tid & 63;
  int row = nt * 16 + (l & 15);
  int k = ks * 32 + (l >> 4) * 8;
  const float* src = wout + (size_t)row * 2048 + 1024 + k;
  float4 a = *(const float4*)src;
  float4 b = *(const float4*)(src + 4);
  __half o[8] = {__float2half(a.x), __float2half(a.y), __float2half(a.z), __float2half(a.w),
                 __float2half(b.x), __float2half(b.y), __float2half(b.z), __float2half(b.w)};
  *(float4*)(wpo + (((size_t)nt * 32 + ks) * 64 + l) * 8) = *(float4*)o;
}

__global__ __launch_bounds__(256) void k_bias_r(const float* __restrict__ bih,
                                                const float* __restrict__ bhh,
                                                float* __restrict__ biasr) {
  int i = blockIdx.x * 256 + threadIdx.x;
  int u = i >> 2, g = i & 3;
  biasr[i] = bih[g * 1024 + u] + bhh[g * 1024 + u];
}

// MFMA precompute GEMM: [4096 x 1024] fp32 @ [1024 x 2048] f16.
// Block = 64m x 128n, 256 thr (4 waves); wave w owns m-subtile w, 8 n-subtiles.
// n0<1024 -> kpre[m][n] row-major ; else -> cwt[b][n-1024][s], m=b*128+s.
__global__ __launch_bounds__(256) void k_pregemm(const float* __restrict__ Af,
                                                 const __half* __restrict__ Bh,
                                                 __half* __restrict__ kpre,
                                                 __half* __restrict__ cwt) {
  __shared__ __half As[64 * 40];    // [m][k], stride 40 halves
  __shared__ __half Bs[128 * 40];   // [n][k] transposed, stride 40
  int tid = threadIdx.x;
  int w = tid >> 6, l = tid & 63;
  int rl = l & 15, kg = l >> 4;
  int m0 = blockIdx.x * 64;
  int n0 = blockIdx.y * 128;
  f32x4 acc[8] = {};

  int am = tid >> 2, akq = (tid & 3) * 8;       // A staging: row, k-offset
  int bkr = tid >> 4, bnc = tid & 15;           // B staging: k-row, n-octet

  for (int k0 = 0; k0 < 1024; k0 += 32) {
    // stage A 64x32 fp32 -> f16
    const float* ap = Af + (size_t)(m0 + am) * 1024 + k0 + akq;
    float4 a0 = *(const float4*)ap;
    float4 a1 = *(const float4*)(ap + 4);
    __half o8[8] = {__float2half(a0.x), __float2half(a0.y), __float2half(a0.z), __float2half(a0.w),
                    __float2half(a1.x), __float2half(a1.y), __float2half(a1.z), __float2half(a1.w)};
    *(float4*)&As[am * 40 + akq] = *(float4*)o8;
    // stage B 32x128 -> transposed [n][k]
#pragma unroll
    for (int h2 = 0; h2 < 2; ++h2) {
      int krr = bkr + h2 * 16;
      f16x8 bv = *(const f16x8*)(Bh + (size_t)(k0 + krr) * 2048 + n0 + bnc * 8);
#pragma unroll
      for (int e = 0; e < 8; ++e) Bs[(bnc * 8 + e) * 40 + krr] = (__half)(float)bv[e];
    }
    __syncthreads();
    f16x8 af = *(const f16x8*)&As[(w * 16 + rl) * 40 + kg * 8];
#pragma unroll
    for (int nn = 0; nn < 8; ++nn) {
      f16x8 bf = *(const f16x8*)&Bs[(nn * 16 + rl) * 40 + kg * 8];
      acc[nn] = __builtin_amdgcn_mfma_f32_16x16x32_f16(af, bf, acc[nn], 0, 0, 0);
    }
    __syncthreads();
  }

  if (blockIdx.y < 8) {
#pragma unroll
    for (int nn = 0; nn < 8; ++nn)
#pragma unroll
      for (int r = 0; r < 4; ++r) {
        int m = m0 + w * 16 + kg * 4 + r;
        kpre[(size_t)m * 1024 + n0 + nn * 16 + rl] = __float2half(acc[nn][r]);
      }
  } else {
    int b = m0 >> 7;
    int nlb = n0 - 1024;
#pragma unroll
    for (int nn = 0; nn < 8; ++nn)
#pragma unroll
      for (int r = 0; r < 4; ++r) {
        int s = (m0 & 127) + w * 16 + kg * 4 + r;
        int nl = nlb + nn * 16 + rl;
        cwt[((size_t)(b << 10) + nl) * 128 + s] = __float2half(acc[nn][r]);
      }
  }
}

// ---------------- flat-release padded half-barrier ----------------
// Per half (128 blocks): B = bar + half*4096 (u32). Every word on its own
// 256B line:
//   part_ctr[p] = B[p*64]        p=0..7   (16 blocks each)
//   glob_ctr    = B[512]
//   part_rel[p] = B[1024+p*64]
//   poison      = B[2048]
// Last arriver (global ctr hits gen*8) writes all 8 part_rel words directly.

__device__ __forceinline__ void halfbar(unsigned* B, int hblk, unsigned gen) {
  __syncthreads();
  if (threadIdx.x == 0) {
    int p = hblk >> 4;
    unsigned a = __hip_atomic_fetch_add(&B[p * 64], 1u,
                                        __ATOMIC_RELAXED, __HIP_MEMORY_SCOPE_AGENT);
    if (a == gen * 16u - 1u) {               // last of partition for this gen
      unsigned g2 = __hip_atomic_fetch_add(&B[512], 1u,
                                           __ATOMIC_RELAXED, __HIP_MEMORY_SCOPE_AGENT);
      if (g2 == gen * 8u - 1u) {             // last partition: release all
#pragma unroll
        for (int q = 0; q < 8; ++q) astore32(&B[1024 + q * 64], gen);
      }
    }
    unsigned spins = 0;
    while (aload32u(&B[1024 + p * 64]) < gen) {
      __builtin_amdgcn_s_sleep(1);
      if ((++spins & 255u) == 0u) {
        if (aload32u(&B[2048]) != 0u) break;
        if (spins > 2000000u) { astore32(&B[2048], 1u); break; }
      }
    }
    asm volatile("" ::: "memory");
  }
  __syncthreads();
}

// ---------------- persistent kernel ----------------
// Two independent half-grids: half = blk>>7 (batches half*16..+15), hblk=blk&127.
// LDS map:
//  A: inp 16x6160B [0,98560) | redA [98560,104704)
//  B: hsl 16x2064B [0,33024) | redC [33024,41216)   (redC persists into C)
//  C: al [41216,49664) | cx [49664,51712) | reads redC

__global__ __launch_bounds__(512, 2) void k_persist(
    const __half* __restrict__ xf, const f16x8* __restrict__ wp,
    const f16x8* __restrict__ whp, const __half* __restrict__ kpre,
    const __half* __restrict__ cwt, const float* __restrict__ biasr,
    const float* __restrict__ bout, __half* __restrict__ hbuf,
    __half* __restrict__ attn, float* __restrict__ scores,
    float* __restrict__ out, unsigned* __restrict__ bar) {
  __shared__ __align__(16) char smem[104704];
  int tid = threadIdx.x;
  int blk = blockIdx.x;
  int half = blk >> 7, hblk = blk & 127;
  unsigned* Bbar = bar + half * 4096;
  int w = tid >> 6, l = tid & 63;
  int rl = l & 15, kg = l >> 4;

  // ---- phase A roles
  int rblk = hblk, bh2 = half;
  int mh = w & 1, kq = w >> 1;
  int mtA = rblk * 2 + mh;

  f16x8 wa[24];
#pragma unroll
  for (int q = 0; q < 24; ++q)
    wa[q] = wp[((size_t)mtA * 96 + kq * 24 + q) * 64 + l];

  // ---- phase B/C roles: nt pairs duplicate (hblk even/odd)
  int nt = hblk >> 1, bhc = half;
  f16x8 wc[4];
#pragma unroll
  for (int q = 0; q < 4; ++q)
    wc[q] = whp[(((size_t)nt * 32) + w * 4 + q) * 64 + l];

  float4 bvA = *(const float4*)&biasr[mtA * 16 + kg * 4];   // w<2
  float4 bo4 = *(const float4*)&bout[nt * 16 + kg * 4];     // w==0

  float creg = 0.f;

  __half* inp = (__half*)smem;
  float* redA = (float*)(smem + 98560);
  __half* hsl = (__half*)smem;
  float* redC = (float*)(smem + 33024);
  float* al   = (float*)(smem + 41216);
  float* cx   = (float*)(smem + 49664);

  // phase B roles: scores for batch bbB, rows s0B + w*2 + (l>>5)
  int bbB = half * 16 + (hblk >> 3), s0B = (hblk & 7) * 16;
  int srB = s0B + w * 2 + (l >> 5), lkB = l & 31;
  // loop-invariant kpre rows -> registers (16 VGPR)
  f16x8 kreg[4];
#pragma unroll
  for (int it = 0; it < 4; ++it)
    kreg[it] = *(const f16x8*)(kpre + ((size_t)(bbB * 128 + srB) << 10) + it * 256 + lkB * 8);

  // phase C ctx roles + loop-invariant cwt slice -> registers (32 VGPR)
  int nl2 = tid & 15, bl2 = (tid >> 4) & 15, sh = tid >> 8;
  f16x8 creg8[8];
  {
    const __half* crow = cwt + (((size_t)(bhc * 16 + bl2) << 10) + nt * 16 + nl2) * 128 + sh * 64;
#pragma unroll
    for (int i = 0; i < 8; ++i) creg8[i] = *(const f16x8*)(crow + i * 8);
  }

  // phase A staging roles
  int b0 = tid >> 5, c0 = tid & 31;
  int bbA = bh2 * 16 + b0;

  // T14 preload for t=0
  float4 xv[4], hv4[4];
  {
    const __half* xrow = xf + ((size_t)bbA * 128 + 0) * 1024;
#pragma unroll
    for (int j = 0; j < 4; ++j) {
      xv[j] = *(const float4*)(xrow + (c0 + 32 * j) * 8);
      hv4[j].x = hv4[j].y = hv4[j].z = hv4[j].w = 0.f;
    }
  }

  for (int t = 0; t < 128; ++t) {
    int cur = t & 1;
    __half* hcur = hbuf + cur * 32768;

    // ======== phase A: gates MFMA + cell ========
    {
      char* drow = (char*)inp + b0 * 6160;
      float4 av[4];
      if (t == 0) {
#pragma unroll
        for (int j = 0; j < 4; ++j) av[j].x = av[j].y = av[j].z = av[j].w = 0.f;
      } else {
        const __half* arow = attn + ((size_t)bbA << 10);
#pragma unroll
        for (int j = 0; j < 4; ++j)
          av[j] = aload128(arow + (c0 + 32 * j) * 8);   // coherent
      }
#pragma unroll
      for (int j = 0; j < 4; ++j) {
        *(float4*)(drow + (c0 + 32 * j) * 16) = xv[j];
        *(float4*)(drow + (128 + c0 + 32 * j) * 16) = av[j];
        *(float4*)(drow + (256 + c0 + 32 * j) * 16) = hv4[j];
      }
      __syncthreads();
      f32x4 acc0 = {0, 0, 0, 0}, acc1 = {0, 0, 0, 0};
      const char* brow = (const char*)inp + rl * 6160 + kg * 16;
#pragma unroll
      for (int q = 0; q < 24; q += 2) {
        f16x8 bf0 = *(const f16x8*)(brow + (kq * 24 + q) * 64);
        f16x8 bf1 = *(const f16x8*)(brow + (kq * 24 + q + 1) * 64);
        acc0 = __builtin_amdgcn_mfma_f32_16x16x32_f16(wa[q], bf0, acc0, 0, 0, 0);
        acc1 = __builtin_amdgcn_mfma_f32_16x16x32_f16(wa[q + 1], bf1, acc1, 0, 0, 0);
      }
      f32x4 acc;
      acc[0] = acc0[0] + acc1[0]; acc[1] = acc0[1] + acc1[1];
      acc[2] = acc0[2] + acc1[2]; acc[3] = acc0[3] + acc1[3];
      if (kq >= 1) *(f32x4*)&redA[(((kq - 1) * 2 + mh) * 64 + l) * 4] = acc;
      __syncthreads();
      if (w < 2) {   // kq==0, mh = w
#pragma unroll
        for (int p = 0; p < 3; ++p) {
          f32x4 o = *(f32x4*)&redA[((p * 2 + mh) * 64 + l) * 4];
          acc[0] += o[0]; acc[1] += o[1]; acc[2] += o[2]; acc[3] += o[3];
        }
        float gi = acc[0] + bvA.x;
        float gf = acc[1] + bvA.y;
        float gg = acc[2] + bvA.z;
        float go = acc[3] + bvA.w;
        float si = 1.f / (1.f + __expf(-gi));
        float sf = 1.f / (1.f + __expf(-gf));
        float so = 1.f / (1.f + __expf(-go));
        creg = sf * creg + si * tanhf(gg);
        int u = rblk * 8 + mh * 4 + kg;
        int b = bh2 * 16 + rl;
        __half hv = __float2half(so * tanhf(creg));
        astore16(&hcur[((size_t)b << 10) + u], *(unsigned short*)&hv);   // coherent
      }
    }
    halfbar(Bbar, hblk, 3 * t + 1);

    // ======== phase B: stage h once + scores + h-proj MFMA ========
    {
      // stage h for 16 batches of this half (coherent reads)
#pragma unroll
      for (int i2 = 0; i2 < 4; ++i2) {
        int f = i2 * 512 + tid;
        int b2 = f >> 7, u2 = f & 127;
        const __half* s = hcur + (((size_t)bhc * 16 + b2) << 10) + u2 * 8;
        char* d = (char*)hsl + b2 * 2064 + u2 * 16;
        ((u64*)d)[0] = aload64(s);
        ((u64*)d)[1] = aload64(s + 4);
      }
      __syncthreads();
      // scores: row srB of batch bbB, kpre from registers
      {
        int blB = hblk >> 3;    // local batch index in hsl
        const char* hrow = (const char*)hsl + blB * 2064;
        float p = 0.f;
#pragma unroll
        for (int it = 0; it < 4; ++it) {
          f16x8 hv = *(const f16x8*)(hrow + (it * 256 + lkB * 8) * 2);
          f16x8 kv = kreg[it];
#pragma unroll
          for (int e = 0; e < 8; ++e) p = fmaf((float)kv[e], (float)hv[e], p);
        }
#pragma unroll
        for (int off = 16; off; off >>= 1) p += __shfl_xor(p, off);
        if (lkB == 0) astore32(&scores[bbB * 128 + srB], __float_as_uint(p));  // coherent
      }
      // h-proj MFMA (K split across 8 waves); redC persists into phase C
      {
        f32x4 acc2 = {0, 0, 0, 0};
        const char* brow2 = (const char*)hsl + rl * 2064 + kg * 16;
#pragma unroll
        for (int q = 0; q < 4; ++q) {
          f16x8 bf = *(const f16x8*)(brow2 + (w * 4 + q) * 64);
          acc2 = __builtin_amdgcn_mfma_f32_16x16x32_f16(wc[q], bf, acc2, 0, 0, 0);
        }
        *(f32x4*)&redC[(w * 64 + l) * 4] = acc2;
      }
    }
    halfbar(Bbar, hblk, 3 * t + 2);

    // ======== phase C: softmax + ctx + combine + tanh ========
    {
      // softmax: 32 lanes per batch — coherent score reads
      {
        int bl = tid >> 5, lj = tid & 31;
        const float* srow = scores + (bhc * 16 + bl) * 128;
        float4 sv = aload128(srow + lj * 4);
        float m = fmaxf(fmaxf(sv.x, sv.y), fmaxf(sv.z, sv.w));
#pragma unroll
        for (int off = 16; off; off >>= 1) m = fmaxf(m, __shfl_xor(m, off));
        float e0 = __expf(sv.x - m), e1 = __expf(sv.y - m);
        float e2 = __expf(sv.z - m), e3 = __expf(sv.w - m);
        float s = e0 + e1 + e2 + e3;
#pragma unroll
        for (int off = 16; off; off >>= 1) s += __shfl_xor(s, off);
        float inv = 1.f / s;
        float4 av2 = {e0 * inv, e1 * inv, e2 * inv, e3 * inv};
        *(float4*)&al[bl * 132 + lj * 4] = av2;
      }
      __syncthreads();
      // ctx partials: (nl2, bl2, sh) with cwt in registers
      {
        const float* arow2 = &al[bl2 * 132 + sh * 64];
        float pc = 0.f;
#pragma unroll
        for (int i = 0; i < 8; ++i) {
          float4 a0 = *(const float4*)(arow2 + i * 8);
          float4 a1 = *(const float4*)(arow2 + i * 8 + 4);
          f16x8 cv = creg8[i];
          pc = fmaf(a0.x, (float)cv[0], pc);
          pc = fmaf(a0.y, (float)cv[1], pc);
          pc = fmaf(a0.z, (float)cv[2], pc);
          pc = fmaf(a0.w, (float)cv[3], pc);
          pc = fmaf(a1.x, (float)cv[4], pc);
          pc = fmaf(a1.y, (float)cv[5], pc);
          pc = fmaf(a1.z, (float)cv[6], pc);
          pc = fmaf(a1.w, (float)cv[7], pc);
        }
        cx[sh * 256 + bl2 * 16 + nl2] = pc;
      }
      __syncthreads();
      if (w == 0) {
        f32x4 acc2 = {0, 0, 0, 0};
#pragma unroll
        for (int p3 = 0; p3 < 8; ++p3) {
          f32x4 o = *(f32x4*)&redC[(p3 * 64 + l) * 4];
          acc2[0] += o[0]; acc2[1] += o[1]; acc2[2] += o[2]; acc2[3] += o[3];
        }
        int bfin = bhc * 16 + rl;
        int n0 = nt * 16 + kg * 4;
        float vo[4];
#pragma unroll
        for (int r = 0; r < 4; ++r) {
          float cv2 = cx[rl * 16 + kg * 4 + r] + cx[256 + rl * 16 + kg * 4 + r];
          float bb2 = (r == 0) ? bo4.x : (r == 1) ? bo4.y : (r == 2) ? bo4.z : bo4.w;
          vo[r] = tanhf(acc2[r] + cv2 + bb2);
        }
        __half o4[4] = {__float2half(vo[0]), __float2half(vo[1]),
                        __float2half(vo[2]), __float2half(vo[3])};
        astore64(&attn[((size_t)bfin << 10) + n0], *(u64*)o4);   // coherent
        float4 ov = {vo[0], vo[1], vo[2], vo[3]};
        *(float4*)&out[(((size_t)bfin * 128 + t) << 10) + n0] = ov;
      }
    }

    // T14 preload for t+1: x (plain) and h (coherent, final since bar 3t+1)
    if (t < 127) {
      const __half* xrow = xf + ((size_t)bbA * 128 + (t + 1)) * 1024;
      const __half* hrow = hcur + ((size_t)bbA << 10);
#pragma unroll
      for (int j = 0; j < 4; ++j) {
        xv[j] = *(const float4*)(xrow + (c0 + 32 * j) * 8);
        hv4[j] = aload128(hrow + (c0 + 32 * j) * 8);
      }
    }
    halfbar(Bbar, hblk, 3 * t + 3);
  }
}

// ---------------- launcher ----------------

extern "C" void kernel_launch(void* const* d_in, const int* in_sizes, int n_in,
                              void* d_out, int out_size, void* d_ws, size_t ws_size,
                              hipStream_t stream) {
  const float* x    = (const float*)d_in[0];
  const float* ctxp = (const float*)d_in[1];
  const float* wih  = (const float*)d_in[2];
  const float* whh  = (const float*)d_in[3];
  const float* bih  = (const float*)d_in[4];
  const float* bhh  = (const float*)d_in[5];
  const float* wq   = (const float*)d_in[6];
  const float* wout = (const float*)d_in[7];
  const float* bo   = (const float*)d_in[8];
  float* out = (float*)d_out;
  char* ws = (char*)d_ws;

  __half* xf    = (__half*)(ws + OFF_XF16);
  __half* wpq   = (__half*)(ws + OFF_WP);
  __half* whpq  = (__half*)(ws + OFF_WHP);
  __half* bcat  = (__half*)(ws + OFF_BCAT);
  __half* kpre  = (__half*)(ws + OFF_KPRE);
  __half* cwt   = (__half*)(ws + OFF_CWT);
  float*  biasr = (float*)(ws + OFF_BIASR);
  __half* hbuf  = (__half*)(ws + OFF_H2);
  __half* attn  = (__half*)(ws + OFF_ATTN);
  float*  sc    = (float*)(ws + OFF_SC);
  unsigned* bar = (unsigned*)(ws + OFF_BAR);

  hipMemsetAsync(ws + OFF_BAR, 0, 32768, stream);

  hipLaunchKernelGGL(k_cvt_x, dim3(4096), dim3(256), 0, stream, x, xf);
  hipLaunchKernelGGL(k_build_bcat, dim3(8, 1024), dim3(256), 0, stream, wq, wout, bcat);
  hipLaunchKernelGGL(k_pack_wp, dim3(256, 24), dim3(256), 0, stream, wih, whh, wpq);
  hipLaunchKernelGGL(k_pack_whp, dim3(64, 8), dim3(256), 0, stream, wout, whpq);
  hipLaunchKernelGGL(k_bias_r, dim3(16), dim3(256), 0, stream, bih, bhh, biasr);
  hipLaunchKernelGGL(k_pregemm, dim3(64, 16), dim3(256), 0, stream, ctxp, bcat, kpre, cwt);

  const f16x8* wpv = (const f16x8*)wpq;
  const f16x8* whpv = (const f16x8*)whpq;
  const __half* xfc = xf;
  const __half* kprec = kpre;
  const __half* cwtc = cwt;
  const float* biasrc = biasr;
  const float* boc = bo;
  void* args[] = {(void*)&xfc, (void*)&wpv, (void*)&whpv, (void*)&kprec, (void*)&cwtc,
                  (void*)&biasrc, (void*)&boc, (void*)&hbuf, (void*)&attn, (void*)&sc,
                  (void*)&out, (void*)&bar};
  hipLaunchCooperativeKernel((void*)k_persist, dim3(256), dim3(512), args, 0, stream);
}

// Round 9
// 2026.754 us; speedup vs baseline: 20.4329x; 1.1696x over previous
//
#include <hip/hip_runtime.h>
#include <hip/hip_fp16.h>

// B=32, T=128, Din=H=C=1024, S=128.
// R9: persistent cooperative kernel, two independent 128-block half-grids.
//  vs R8: (1) REVERT register-resident kpre/cwt (compiler rematerialized ->
//  FETCH 228->734MB, +109us; per-step coalesced loads restored); (2) split
//  arrive/wait barriers: h-proj MFMA runs in the bar2 window, x/h preload +
//  inp LDS staging runs in the bar3 window (phase-A critical path = attn load
//  + MFMA only). Keep: flat release, MFMA pregemm, h-proj in phase B.
//
// MFMA 16x16x32_f16 layout (guide §3, m89-verified):
//   A: lane l, elem j -> A[l&15][(l>>4)*8+j]
//   B: lane l, elem j -> B[(l>>4)*8+j][l&15]
//   D: lane l, reg  r -> D[(l>>4)*4+r][l&15]

typedef _Float16 f16x8 __attribute__((ext_vector_type(8)));
typedef float f32x4 __attribute__((ext_vector_type(4)));
typedef unsigned long long u64;

// ---- workspace layout (bytes) ----
#define OFF_XF16  ((size_t)0)           // [32][128][1024] f16     8,388,608
#define OFF_WP    ((size_t)8388608)     // [256][96][64][8] f16   25,165,824
#define OFF_WHP   ((size_t)33554432)    // [64][32][64][8] f16     2,097,152
#define OFF_BCAT  ((size_t)35651584)    // [1024][2048] f16        4,194,304
#define OFF_KPRE  ((size_t)39845888)    // [4096][1024] f16 row-major 8,388,608
#define OFF_CWT   ((size_t)48234496)    // [32][1024][128] f16     8,388,608
#define OFF_BIASR ((size_t)56623104)    // [4096] f32                 16,384
#define OFF_H2    ((size_t)56770560)    // [2][32][1024] f16         131,072
#define OFF_ATTN  ((size_t)56901632)    // [32][1024] f16             65,536
#define OFF_SC    ((size_t)56967168)    // [32][128] f32              16,384
#define OFF_BAR   ((size_t)56983552)    // 32 KB barrier state (2 halves x 16KB)

// ---- agent-scope coherent access helpers (bypass non-coherent L2) ----
__device__ __forceinline__ u64 aload64(const void* p) {
  return __hip_atomic_load((const u64*)p, __ATOMIC_RELAXED, __HIP_MEMORY_SCOPE_AGENT);
}
__device__ __forceinline__ unsigned aload32u(const unsigned* p) {
  return __hip_atomic_load(p, __ATOMIC_RELAXED, __HIP_MEMORY_SCOPE_AGENT);
}
__device__ __forceinline__ void astore32(void* p, unsigned v) {
  __hip_atomic_store((unsigned*)p, v, __ATOMIC_RELAXED, __HIP_MEMORY_SCOPE_AGENT);
}
__device__ __forceinline__ void astore64(void* p, u64 v) {
  __hip_atomic_store((u64*)p, v, __ATOMIC_RELAXED, __HIP_MEMORY_SCOPE_AGENT);
}
__device__ __forceinline__ void astore16(void* p, unsigned short v) {
  __hip_atomic_store((unsigned short*)p, v, __ATOMIC_RELAXED, __HIP_MEMORY_SCOPE_AGENT);
}
__device__ __forceinline__ float4 aload128(const void* p) {
  float4 v;
  ((u64*)&v)[0] = aload64(p);
  ((u64*)&v)[1] = aload64((const char*)p + 8);
  return v;
}

// ---------------- one-time kernels ----------------

__global__ __launch_bounds__(256) void k_cvt_x(const float* __restrict__ x, __half* __restrict__ xf) {
  int i = blockIdx.x * 256 + threadIdx.x;
  float4 v = ((const float4*)x)[i];
  __half h4[4] = {__float2half(v.x), __float2half(v.y), __float2half(v.z), __float2half(v.w)};
  ((float2*)xf)[i] = *(float2*)h4;
}

__global__ __launch_bounds__(256) void k_build_bcat(const float* __restrict__ wq,
                                                    const float* __restrict__ wout,
                                                    __half* __restrict__ bcat) {
  int j = blockIdx.x * 256 + threadIdx.x;
  int c = blockIdx.y;
  float v = (j < 1024) ? wq[c * 1024 + j] : wout[(size_t)(j - 1024) * 2048 + c];
  bcat[c * 2048 + j] = __float2half(v);
}

// pack gate weights into MFMA A-fragment stream: wp[mt][ks][l][8]
// packed row r' = mt*16 + (l&15); original row = gate*1024 + u, r' = u*4+gate
__global__ __launch_bounds__(256) void k_pack_wp(const float* __restrict__ wih,
                                                 const float* __restrict__ whh,
                                                 __half* __restrict__ wpo) {
  int mt = blockIdx.x;
  int tid = threadIdx.x;
  int ks = blockIdx.y * 4 + (tid >> 6);
  int l = tid & 63;
  int rp = mt * 16 + (l & 15);
  int u = rp >> 2, g = rp & 3;
  int row = g * 1024 + u;
  int k = ks * 32 + (l >> 4) * 8;
  const float* src = (k < 2048) ? (wih + (size_t)row * 2048 + k)
                                : (whh + (size_t)row * 1024 + (k - 2048));
  float4 a = *(const float4*)src;
  float4 b = *(const float4*)(src + 4);
  __half o[8] = {__float2half(a.x), __float2half(a.y), __float2half(a.z), __float2half(a.w),
                 __float2half(b.x), __float2half(b.y), __float2half(b.z), __float2half(b.w)};
  *(float4*)(wpo + (((size_t)mt * 96 + ks) * 64 + l) * 8) = *(float4*)o;
}

__global__ __launch_bounds__(256) void k_pack_whp(const float* __restrict__ wout,
                                                  __half* __restrict__ wpo) {
  int nt = blockIdx.x;
  int tid = threadIdx.x;
  int ks = blockIdx.y * 4 + (tid >> 6);
  int l = tid & 63;
  int row = nt * 16 + (l & 15);
  int k = ks * 32 + (l >> 4) * 8;
  const float* src = wout + (size_t)row * 2048 + 1024 + k;
  float4 a = *(const float4*)src;
  float4 b = *(const float4*)(src + 4);
  __half o[8] = {__float2half(a.x), __float2half(a.y), __float2half(a.z), __float2half(a.w),
                 __float2half(b.x), __float2half(b.y), __float2half(b.z), __float2half(b.w)};
  *(float4*)(wpo + (((size_t)nt * 32 + ks) * 64 + l) * 8) = *(float4*)o;
}

__global__ __launch_bounds__(256) void k_bias_r(const float* __restrict__ bih,
                                                const float* __restrict__ bhh,
                                                float* __restrict__ biasr) {
  int i = blockIdx.x * 256 + threadIdx.x;
  int u = i >> 2, g = i & 3;
  biasr[i] = bih[g * 1024 + u] + bhh[g * 1024 + u];
}

// MFMA precompute GEMM: [4096 x 1024] fp32 @ [1024 x 2048] f16.
// Block = 64m x 128n, 256 thr (4 waves); wave w owns m-subtile w, 8 n-subtiles.
// n0<1024 -> kpre[m][n] row-major ; else -> cwt[b][n-1024][s], m=b*128+s.
__global__ __launch_bounds__(256) void k_pregemm(const float* __restrict__ Af,
                                                 const __half* __restrict__ Bh,
                                                 __half* __restrict__ kpre,
                                                 __half* __restrict__ cwt) {
  __shared__ __half As[64 * 40];    // [m][k], stride 40 halves
  __shared__ __half Bs[128 * 40];   // [n][k] transposed, stride 40
  int tid = threadIdx.x;
  int w = tid >> 6, l = tid & 63;
  int rl = l & 15, kg = l >> 4;
  int m0 = blockIdx.x * 64;
  int n0 = blockIdx.y * 128;
  f32x4 acc[8] = {};

  int am = tid >> 2, akq = (tid & 3) * 8;       // A staging: row, k-offset
  int bkr = tid >> 4, bnc = tid & 15;           // B staging: k-row, n-octet

  for (int k0 = 0; k0 < 1024; k0 += 32) {
    // stage A 64x32 fp32 -> f16
    const float* ap = Af + (size_t)(m0 + am) * 1024 + k0 + akq;
    float4 a0 = *(const float4*)ap;
    float4 a1 = *(const float4*)(ap + 4);
    __half o8[8] = {__float2half(a0.x), __float2half(a0.y), __float2half(a0.z), __float2half(a0.w),
                    __float2half(a1.x), __float2half(a1.y), __float2half(a1.z), __float2half(a1.w)};
    *(float4*)&As[am * 40 + akq] = *(float4*)o8;
    // stage B 32x128 -> transposed [n][k]
#pragma unroll
    for (int h2 = 0; h2 < 2; ++h2) {
      int krr = bkr + h2 * 16;
      f16x8 bv = *(const f16x8*)(Bh + (size_t)(k0 + krr) * 2048 + n0 + bnc * 8);
#pragma unroll
      for (int e = 0; e < 8; ++e) Bs[(bnc * 8 + e) * 40 + krr] = (__half)(float)bv[e];
    }
    __syncthreads();
    f16x8 af = *(const f16x8*)&As[(w * 16 + rl) * 40 + kg * 8];
#pragma unroll
    for (int nn = 0; nn < 8; ++nn) {
      f16x8 bf = *(const f16x8*)&Bs[(nn * 16 + rl) * 40 + kg * 8];
      acc[nn] = __builtin_amdgcn_mfma_f32_16x16x32_f16(af, bf, acc[nn], 0, 0, 0);
    }
    __syncthreads();
  }

  if (blockIdx.y < 8) {
#pragma unroll
    for (int nn = 0; nn < 8; ++nn)
#pragma unroll
      for (int r = 0; r < 4; ++r) {
        int m = m0 + w * 16 + kg * 4 + r;
        kpre[(size_t)m * 1024 + n0 + nn * 16 + rl] = __float2half(acc[nn][r]);
      }
  } else {
    int b = m0 >> 7;
    int nlb = n0 - 1024;
#pragma unroll
    for (int nn = 0; nn < 8; ++nn)
#pragma unroll
      for (int r = 0; r < 4; ++r) {
        int s = (m0 & 127) + w * 16 + kg * 4 + r;
        int nl = nlb + nn * 16 + rl;
        cwt[((size_t)(b << 10) + nl) * 128 + s] = __float2half(acc[nn][r]);
      }
  }
}

// ---------------- split arrive/wait padded half-barrier ----------------
// Per half (128 blocks): B = bar + half*4096 (u32). Every word on its own
// 256B line:
//   part_ctr[p] = B[p*64]        p=0..7   (16 blocks each)
//   glob_ctr    = B[512]
//   part_rel[p] = B[1024+p*64]
//   poison      = B[2048]
// Last arriver (global ctr hits gen*8) writes all 8 part_rel words.

__device__ __forceinline__ void bar_arrive(unsigned* B, int hblk, unsigned gen) {
  __syncthreads();   // all block stores drained (compiler emits vmcnt before s_barrier)
  if (threadIdx.x == 0) {
    int p = hblk >> 4;
    unsigned a = __hip_atomic_fetch_add(&B[p * 64], 1u,
                                        __ATOMIC_RELAXED, __HIP_MEMORY_SCOPE_AGENT);
    if (a == gen * 16u - 1u) {               // last of partition for this gen
      unsigned g2 = __hip_atomic_fetch_add(&B[512], 1u,
                                           __ATOMIC_RELAXED, __HIP_MEMORY_SCOPE_AGENT);
      if (g2 == gen * 8u - 1u) {             // last partition: release all
#pragma unroll
        for (int q = 0; q < 8; ++q) astore32(&B[1024 + q * 64], gen);
      }
    }
  }
}

__device__ __forceinline__ void bar_wait(unsigned* B, int hblk, unsigned gen) {
  if (threadIdx.x == 0) {
    int p = hblk >> 4;
    unsigned spins = 0;
    while (aload32u(&B[1024 + p * 64]) < gen) {
      __builtin_amdgcn_s_sleep(1);
      if ((++spins & 255u) == 0u) {
        if (aload32u(&B[2048]) != 0u) break;
        if (spins > 2000000u) { astore32(&B[2048], 1u); break; }
      }
    }
    asm volatile("" ::: "memory");
  }
  __syncthreads();
}

__device__ __forceinline__ void halfbar(unsigned* B, int hblk, unsigned gen) {
  bar_arrive(B, hblk, gen);
  bar_wait(B, hblk, gen);
}

// ---------------- persistent kernel ----------------
// Two independent half-grids: half = blk>>7 (batches half*16..+15), hblk=blk&127.
// LDS map:
//  A: inp 16x6160B [0,98560) | redA [98560,104704)
//  B: hsl 16x2064B [0,33024) | redC [33024,41216)   (redC persists into C)
//  C: al [41216,49664) | cx [49664,51712) | reads redC
//  C->A window: x/h written into inp (after arrive(bar3) syncthreads, so all
//  al/cx/redC/hsl readers are done; phase A consumes inp before B re-clobbers).

__global__ __launch_bounds__(512, 2) void k_persist(
    const __half* __restrict__ xf, const f16x8* __restrict__ wp,
    const f16x8* __restrict__ whp, const __half* __restrict__ kpre,
    const __half* __restrict__ cwt, const float* __restrict__ biasr,
    const float* __restrict__ bout, __half* __restrict__ hbuf,
    __half* __restrict__ attn, float* __restrict__ scores,
    float* __restrict__ out, unsigned* __restrict__ bar) {
  __shared__ __align__(16) char smem[104704];
  int tid = threadIdx.x;
  int blk = blockIdx.x;
  int half = blk >> 7, hblk = blk & 127;
  unsigned* Bbar = bar + half * 4096;
  int w = tid >> 6, l = tid & 63;
  int rl = l & 15, kg = l >> 4;

  // ---- phase A roles
  int rblk = hblk, bh2 = half;
  int mh = w & 1, kq = w >> 1;
  int mtA = rblk * 2 + mh;

  f16x8 wa[24];
#pragma unroll
  for (int q = 0; q < 24; ++q)
    wa[q] = wp[((size_t)mtA * 96 + kq * 24 + q) * 64 + l];

  // ---- phase B/C roles: nt pairs duplicate (hblk even/odd)
  int nt = hblk >> 1, bhc = half;
  f16x8 wc[4];
#pragma unroll
  for (int q = 0; q < 4; ++q)
    wc[q] = whp[(((size_t)nt * 32) + w * 4 + q) * 64 + l];

  float4 bvA = *(const float4*)&biasr[mtA * 16 + kg * 4];   // w<2
  float4 bo4 = *(const float4*)&bout[nt * 16 + kg * 4];     // w==0

  float creg = 0.f;

  __half* inp = (__half*)smem;
  float* redA = (float*)(smem + 98560);
  __half* hsl = (__half*)smem;
  float* redC = (float*)(smem + 33024);
  float* al   = (float*)(smem + 41216);
  float* cx   = (float*)(smem + 49664);

  // phase B roles: scores for batch bbB, row srB
  int bbB = half * 16 + (hblk >> 3), s0B = (hblk & 7) * 16;
  int srB = s0B + w * 2 + (l >> 5), lkB = l & 31;

  // phase C ctx roles
  int nl2 = tid & 15, bl2 = (tid >> 4) & 15, sh = tid >> 8;

  // phase A staging roles
  int b0 = tid >> 5, c0 = tid & 31;
  int bbA = bh2 * 16 + b0;

  // pre-loop: stage x(t=0) and h=0 into inp
  {
    char* drow = (char*)inp + b0 * 6160;
    const __half* xrow = xf + ((size_t)bbA * 128 + 0) * 1024;
    float4 z = {0.f, 0.f, 0.f, 0.f};
#pragma unroll
    for (int j = 0; j < 4; ++j) {
      float4 xv = *(const float4*)(xrow + (c0 + 32 * j) * 8);
      *(float4*)(drow + (c0 + 32 * j) * 16) = xv;
      *(float4*)(drow + (256 + c0 + 32 * j) * 16) = z;
    }
  }

  for (int t = 0; t < 128; ++t) {
    int cur = t & 1;
    __half* hcur = hbuf + cur * 32768;

    // ======== phase A: attn staging + gates MFMA + cell ========
    {
      char* drow = (char*)inp + b0 * 6160;
      if (t == 0) {
        float4 z = {0.f, 0.f, 0.f, 0.f};
#pragma unroll
        for (int j = 0; j < 4; ++j)
          *(float4*)(drow + (128 + c0 + 32 * j) * 16) = z;
      } else {
        const __half* arow = attn + ((size_t)bbA << 10);
        float4 av[4];
#pragma unroll
        for (int j = 0; j < 4; ++j)
          av[j] = aload128(arow + (c0 + 32 * j) * 8);   // coherent
#pragma unroll
        for (int j = 0; j < 4; ++j)
          *(float4*)(drow + (128 + c0 + 32 * j) * 16) = av[j];
      }
      __syncthreads();
      f32x4 acc0 = {0, 0, 0, 0}, acc1 = {0, 0, 0, 0};
      const char* brow = (const char*)inp + rl * 6160 + kg * 16;
#pragma unroll
      for (int q = 0; q < 24; q += 2) {
        f16x8 bf0 = *(const f16x8*)(brow + (kq * 24 + q) * 64);
        f16x8 bf1 = *(const f16x8*)(brow + (kq * 24 + q + 1) * 64);
        acc0 = __builtin_amdgcn_mfma_f32_16x16x32_f16(wa[q], bf0, acc0, 0, 0, 0);
        acc1 = __builtin_amdgcn_mfma_f32_16x16x32_f16(wa[q + 1], bf1, acc1, 0, 0, 0);
      }
      f32x4 acc;
      acc[0] = acc0[0] + acc1[0]; acc[1] = acc0[1] + acc1[1];
      acc[2] = acc0[2] + acc1[2]; acc[3] = acc0[3] + acc1[3];
      if (kq >= 1) *(f32x4*)&redA[(((kq - 1) * 2 + mh) * 64 + l) * 4] = acc;
      __syncthreads();
      if (w < 2) {   // kq==0, mh = w
#pragma unroll
        for (int p = 0; p < 3; ++p) {
          f32x4 o = *(f32x4*)&redA[((p * 2 + mh) * 64 + l) * 4];
          acc[0] += o[0]; acc[1] += o[1]; acc[2] += o[2]; acc[3] += o[3];
        }
        float gi = acc[0] + bvA.x;
        float gf = acc[1] + bvA.y;
        float gg = acc[2] + bvA.z;
        float go = acc[3] + bvA.w;
        float si = 1.f / (1.f + __expf(-gi));
        float sf = 1.f / (1.f + __expf(-gf));
        float so = 1.f / (1.f + __expf(-go));
        creg = sf * creg + si * tanhf(gg);
        int u = rblk * 8 + mh * 4 + kg;
        int b = bh2 * 16 + rl;
        __half hv = __float2half(so * tanhf(creg));
        astore16(&hcur[((size_t)b << 10) + u], *(unsigned short*)&hv);   // coherent
      }
    }
    halfbar(Bbar, hblk, 3 * t + 1);

    // ======== phase B: stage h + scores; h-proj MFMA in bar2 window ========
    {
#pragma unroll
      for (int i2 = 0; i2 < 4; ++i2) {
        int f = i2 * 512 + tid;
        int b2 = f >> 7, u2 = f & 127;
        const __half* s = hcur + (((size_t)bhc * 16 + b2) << 10) + u2 * 8;
        char* d = (char*)hsl + b2 * 2064 + u2 * 16;
        ((u64*)d)[0] = aload64(s);
        ((u64*)d)[1] = aload64(s + 4);
      }
      __syncthreads();
      // scores: row srB of batch bbB (kpre per-step coalesced loads)
      {
        int blB = hblk >> 3;    // local batch index in hsl
        const char* hrow = (const char*)hsl + blB * 2064;
        const __half* krow = kpre + ((size_t)(bbB * 128 + srB) << 10);
        float p = 0.f;
#pragma unroll
        for (int it = 0; it < 4; ++it) {
          f16x8 kv = *(const f16x8*)(krow + it * 256 + lkB * 8);
          f16x8 hv = *(const f16x8*)(hrow + (it * 256 + lkB * 8) * 2);
#pragma unroll
          for (int e = 0; e < 8; ++e) p = fmaf((float)kv[e], (float)hv[e], p);
        }
#pragma unroll
        for (int off = 16; off; off >>= 1) p += __shfl_xor(p, off);
        if (lkB == 0) astore32(&scores[bbB * 128 + srB], __float_as_uint(p));  // coherent
      }
    }
    bar_arrive(Bbar, hblk, 3 * t + 2);
    {
      // h-proj MFMA while barrier drains; redC persists into phase C
      f32x4 acc2 = {0, 0, 0, 0};
      const char* brow2 = (const char*)hsl + rl * 2064 + kg * 16;
#pragma unroll
      for (int q = 0; q < 4; ++q) {
        f16x8 bf = *(const f16x8*)(brow2 + (w * 4 + q) * 64);
        acc2 = __builtin_amdgcn_mfma_f32_16x16x32_f16(wc[q], bf, acc2, 0, 0, 0);
      }
      *(f32x4*)&redC[(w * 64 + l) * 4] = acc2;
    }
    bar_wait(Bbar, hblk, 3 * t + 2);

    // ======== phase C: softmax + ctx + combine + tanh ========
    {
      // softmax: 32 lanes per batch — coherent score reads
      {
        int bl = tid >> 5, lj = tid & 31;
        const float* srow = scores + (bhc * 16 + bl) * 128;
        float4 sv = aload128(srow + lj * 4);
        float m = fmaxf(fmaxf(sv.x, sv.y), fmaxf(sv.z, sv.w));
#pragma unroll
        for (int off = 16; off; off >>= 1) m = fmaxf(m, __shfl_xor(m, off));
        float e0 = __expf(sv.x - m), e1 = __expf(sv.y - m);
        float e2 = __expf(sv.z - m), e3 = __expf(sv.w - m);
        float s = e0 + e1 + e2 + e3;
#pragma unroll
        for (int off = 16; off; off >>= 1) s += __shfl_xor(s, off);
        float inv = 1.f / s;
        float4 av2 = {e0 * inv, e1 * inv, e2 * inv, e3 * inv};
        *(float4*)&al[bl * 132 + lj * 4] = av2;
      }
      __syncthreads();
      // ctx partials: (nl2, bl2, sh), cwt per-step coalesced loads
      {
        const __half* crow = cwt + (((size_t)(bhc * 16 + bl2) << 10) + nt * 16 + nl2) * 128 + sh * 64;
        const float* arow2 = &al[bl2 * 132 + sh * 64];
        float pc = 0.f;
#pragma unroll
        for (int s2 = 0; s2 < 64; s2 += 8) {
          f16x8 cv = *(const f16x8*)(crow + s2);
#pragma unroll
          for (int e = 0; e < 8; ++e) pc = fmaf(arow2[s2 + e], (float)cv[e], pc);
        }
        cx[sh * 256 + bl2 * 16 + nl2] = pc;
      }
      __syncthreads();
      if (w == 0) {
        f32x4 acc2 = {0, 0, 0, 0};
#pragma unroll
        for (int p3 = 0; p3 < 8; ++p3) {
          f32x4 o = *(f32x4*)&redC[(p3 * 64 + l) * 4];
          acc2[0] += o[0]; acc2[1] += o[1]; acc2[2] += o[2]; acc2[3] += o[3];
        }
        int bfin = bhc * 16 + rl;
        int n0 = nt * 16 + kg * 4;
        float vo[4];
#pragma unroll
        for (int r = 0; r < 4; ++r) {
          float cv2 = cx[rl * 16 + kg * 4 + r] + cx[256 + rl * 16 + kg * 4 + r];
          float bb2 = (r == 0) ? bo4.x : (r == 1) ? bo4.y : (r == 2) ? bo4.z : bo4.w;
          vo[r] = tanhf(acc2[r] + cv2 + bb2);
        }
        __half o4[4] = {__float2half(vo[0]), __float2half(vo[1]),
                        __float2half(vo[2]), __float2half(vo[3])};
        astore64(&attn[((size_t)bfin << 10) + n0], *(u64*)o4);   // coherent
        float4 ov = {vo[0], vo[1], vo[2], vo[3]};
        *(float4*)&out[(((size_t)bfin * 128 + t) << 10) + n0] = ov;
      }
    }
    bar_arrive(Bbar, hblk, 3 * t + 3);
    // bar3 window: preload x_{t+1} (plain) + h_t (coherent, final since bar1)
    // and stage both into inp LDS (arrive's syncthreads ordered all al/cx/redC
    // readers before these writes).
    if (t < 127) {
      char* drow = (char*)inp + b0 * 6160;
      const __half* xrow = xf + ((size_t)bbA * 128 + (t + 1)) * 1024;
      const __half* hrow = hcur + ((size_t)bbA << 10);
#pragma unroll
      for (int j = 0; j < 4; ++j) {
        float4 xv = *(const float4*)(xrow + (c0 + 32 * j) * 8);
        float4 hv = aload128(hrow + (c0 + 32 * j) * 8);
        *(float4*)(drow + (c0 + 32 * j) * 16) = xv;
        *(float4*)(drow + (256 + c0 + 32 * j) * 16) = hv;
      }
    }
    bar_wait(Bbar, hblk, 3 * t + 3);
  }
}

// ---------------- launcher ----------------

extern "C" void kernel_launch(void* const* d_in, const int* in_sizes, int n_in,
                              void* d_out, int out_size, void* d_ws, size_t ws_size,
                              hipStream_t stream) {
  const float* x    = (const float*)d_in[0];
  const float* ctxp = (const float*)d_in[1];
  const float* wih  = (const float*)d_in[2];
  const float* whh  = (const float*)d_in[3];
  const float* bih  = (const float*)d_in[4];
  const float* bhh  = (const float*)d_in[5];
  const float* wq   = (const float*)d_in[6];
  const float* wout = (const float*)d_in[7];
  const float* bo   = (const float*)d_in[8];
  float* out = (float*)d_out;
  char* ws = (char*)d_ws;

  __half* xf    = (__half*)(ws + OFF_XF16);
  __half* wpq   = (__half*)(ws + OFF_WP);
  __half* whpq  = (__half*)(ws + OFF_WHP);
  __half* bcat  = (__half*)(ws + OFF_BCAT);
  __half* kpre  = (__half*)(ws + OFF_KPRE);
  __half* cwt   = (__half*)(ws + OFF_CWT);
  float*  biasr = (float*)(ws + OFF_BIASR);
  __half* hbuf  = (__half*)(ws + OFF_H2);
  __half* attn  = (__half*)(ws + OFF_ATTN);
  float*  sc    = (float*)(ws + OFF_SC);
  unsigned* bar = (unsigned*)(ws + OFF_BAR);

  hipMemsetAsync(ws + OFF_BAR, 0, 32768, stream);

  hipLaunchKernelGGL(k_cvt_x, dim3(4096), dim3(256), 0, stream, x, xf);
  hipLaunchKernelGGL(k_build_bcat, dim3(8, 1024), dim3(256), 0, stream, wq, wout, bcat);
  hipLaunchKernelGGL(k_pack_wp, dim3(256, 24), dim3(256), 0, stream, wih, whh, wpq);
  hipLaunchKernelGGL(k_pack_whp, dim3(64, 8), dim3(256), 0, stream, wout, whpq);
  hipLaunchKernelGGL(k_bias_r, dim3(16), dim3(256), 0, stream, bih, bhh, biasr);
  hipLaunchKernelGGL(k_pregemm, dim3(64, 16), dim3(256), 0, stream, ctxp, bcat, kpre, cwt);

  const f16x8* wpv = (const f16x8*)wpq;
  const f16x8* whpv = (const f16x8*)whpq;
  const __half* xfc = xf;
  const __half* kprec = kpre;
  const __half* cwtc = cwt;
  const float* biasrc = biasr;
  const float* boc = bo;
  void* args[] = {(void*)&xfc, (void*)&wpv, (void*)&whpv, (void*)&kprec, (void*)&cwtc,
                  (void*)&biasrc, (void*)&boc, (void*)&hbuf, (void*)&attn, (void*)&sc,
                  (void*)&out, (void*)&bar};
  hipLaunchCooperativeKernel((void*)k_persist, dim3(256), dim3(512), args, 0, stream);
}